// Round 8
// baseline (486.371 us; speedup 1.0000x reference)
//
#include <hip/hip_runtime.h>
#include <cmath>

// HyperKGL: N=100000, H=20000, NS=10, D=64, L=2, E=1e6, NB=50000
// R7 -> R8: k_matfuse was LDS-capped (78KB -> 2 blocks/CU, 17% occ, latency-bound).
// W matrices are 16KB each and L1/L2-resident -> read W straight from global,
// keep only the A tiles in LDS (12.5KB) -> 8 blocks/CU. Grid 512 -> 2048.

#define EPSF 1e-9f
#define NSLOT 40960
#define SENT 0xFFFFFFFFu
typedef unsigned long long ull;

__device__ __forceinline__ float group16_sum(float v){
  v += __shfl_xor(v, 1, 64);
  v += __shfl_xor(v, 2, 64);
  v += __shfl_xor(v, 4, 64);
  v += __shfl_xor(v, 8, 64);
  return v;
}
__device__ __forceinline__ float xgroup_sum(float v){
  v += __shfl_xor(v, 16, 64);
  v += __shfl_xor(v, 32, 64);
  return v;
}

// ---------------- setup ----------------
__global__ __launch_bounds__(256) void k_copy4(const float4* __restrict__ in, float4* __restrict__ out, int n){
  int i = blockIdx.x*256 + threadIdx.x;
  if (i < n) out[i] = in[i];
}

__global__ __launch_bounds__(256) void k_set_member(const int* __restrict__ idx, int* __restrict__ member, int n){
  int i = blockIdx.x*256 + threadIdx.x;
  if (i < n) member[idx[i]] = 1;
}

__global__ __launch_bounds__(256) void k_build_list(int* __restrict__ member, int* __restrict__ mlist,
                                                    int* __restrict__ mcount, int N){
  int n = blockIdx.x*256 + threadIdx.x;
  if (n < N && member[n]) {
    int p = atomicAdd(mcount, 1);
    mlist[p] = n;
    member[n] = p + 2;   // slot+2 (0 = non-member)
  }
}

// streaming record build, no atomics
__global__ __launch_bounds__(256) void k_rec(const int* __restrict__ sl, const int* __restrict__ member,
                                             ull* __restrict__ rec, int E){
  int e = blockIdx.x*256 + threadIdx.x;
  if (e >= E) return;
  int src = sl[3*e];
  int m = member[src];
  if (m){
    unsigned lo = (unsigned)(m-2) | ((unsigned)sl[3*e+2] << 20);
    rec[e] = (ull)lo | ((ull)(unsigned)sl[3*e+1] << 32);
  } else {
    rec[e] = (ull)SENT << 32;
  }
}

// XCD-windowed histogram for BOTH keys (window = blockIdx&7)
__global__ __launch_bounds__(256) void k_wcount(const ull* __restrict__ rec, const int* __restrict__ mcountp,
    int* __restrict__ cnt_hed, int* __restrict__ cnt_slot, int E){
  int w = blockIdx.x & 7;
  int chunk = blockIdx.x >> 3;
  int nchunk = gridDim.x >> 3;
  int per = (E + nchunk - 1) / nchunk;
  int lo_i = chunk * per;
  int hi_i = min(E, lo_i + per);
  int divs = (*mcountp + 7) >> 3;
  for (int i = lo_i + threadIdx.x; i < hi_i; i += 256){
    ull r = rec[i];
    unsigned hed = (unsigned)(r >> 32);
    if (hed == SENT) continue;
    int slot = (int)(r & 0xFFFFF);
    if ((int)hed / 2500 == w) atomicAdd(&cnt_hed[hed], 1);
    if (slot / divs   == w) atomicAdd(&cnt_slot[slot], 1);
  }
}

// exclusive scan: chunk = 2048 per block
__global__ __launch_bounds__(256) void k_scan1(const int* __restrict__ in, int* __restrict__ out, int n,
                                               int* __restrict__ partials){
  __shared__ int s[256];
  int b = blockIdx.x, t = threadIdx.x;
  int base = b*2048 + t*8;
  int v[8]; int sum = 0;
  #pragma unroll
  for (int j=0;j<8;j++){ int i = base + j; v[j] = (i<n) ? in[i] : 0; sum += v[j]; }
  s[t] = sum;
  __syncthreads();
  for (int o=1;o<256;o<<=1){
    int x = (t>=o) ? s[t-o] : 0;
    __syncthreads();
    s[t] += x;
    __syncthreads();
  }
  int excl = s[t] - sum;
  if (t == 255) partials[b] = s[255];
  int run = excl;
  #pragma unroll
  for (int j=0;j<8;j++){ int i = base + j; if (i<n) out[i] = run; run += v[j]; }
}

__global__ void k_scan2(int* __restrict__ partials, int nb, int* __restrict__ out, int n){
  if (threadIdx.x==0 && blockIdx.x==0){
    int run = 0;
    for (int i=0;i<nb;i++){ int x = partials[i]; partials[i] = run; run += x; }
    out[n] = run;
  }
}

__global__ __launch_bounds__(256) void k_scan3(int* __restrict__ out, const int* __restrict__ partials, int n){
  int i = blockIdx.x*256 + threadIdx.x;
  if (i < n) out[i] += partials[i >> 11];
}

// windowed scatter (XCD-affine). KEY=0: by hed -> edge_hed (payload slot|sem<<20).
// KEY=1: by slot -> edge_src (payload hed|sem<<20).
template<int KEY>
__global__ __launch_bounds__(256) void k_scatter2(const ull* __restrict__ rec,
    const int* __restrict__ mcountp,
    const int* __restrict__ off, int* __restrict__ cur, unsigned* __restrict__ dst, int E){
  int w = blockIdx.x & 7;
  int chunk = blockIdx.x >> 3;
  int nchunk = gridDim.x >> 3;
  int per = (E + nchunk - 1) / nchunk;
  int lo_i = chunk * per;
  int hi_i = min(E, lo_i + per);
  int div = KEY ? ((*mcountp + 7) >> 3) : 2500;
  for (int i = lo_i + threadIdx.x; i < hi_i; i += 256){
    ull r = rec[i];
    unsigned hed = (unsigned)(r >> 32);
    if (hed == SENT) continue;
    unsigned lo = (unsigned)r;
    int slot = lo & 0xFFFFF;
    int key = KEY ? slot : (int)hed;
    if (key / div != w) continue;
    unsigned payload = KEY ? (hed | (lo & 0xFFF00000u)) : lo;
    int p = off[key] + atomicAdd(&cur[key], 1);
    dst[p] = payload;
  }
}

// ---------------- fused gather-matmuls ----------------
// A: gathered ne rows -> nm = ne@Wm, inner1 = ne@Wi1 (one gather, two GEMVs)
__global__ __launch_bounds__(256) void k_rowmatA(const float* __restrict__ ne, const float* __restrict__ Wm,
    const float* __restrict__ Wi1, const int* __restrict__ mlist, const int* __restrict__ mcountp,
    float* __restrict__ nm, float* __restrict__ inner1){
  __shared__ float W1[4096], W2[4096];
  __shared__ float A[16][65];
  int t = threadIdx.x;
  for (int i=t;i<1024;i+=256){ ((float4*)W1)[i] = ((const float4*)Wm)[i]; ((float4*)W2)[i] = ((const float4*)Wi1)[i]; }
  int nrows = *mcountp;
  int ntiles = (nrows + 15) >> 4;
  int rr = t >> 4, cg = t & 15;
  for (int tile = blockIdx.x; tile < ntiles; tile += gridDim.x){
    __syncthreads();
    int r = tile*16 + rr;
    if (r < nrows){
      float4 v = *(const float4*)&ne[(size_t)mlist[r]*64 + cg*4];
      A[rr][cg*4+0]=v.x; A[rr][cg*4+1]=v.y; A[rr][cg*4+2]=v.z; A[rr][cg*4+3]=v.w;
    }
    __syncthreads();
    float a0=0.f,a1=0.f,a2=0.f,a3=0.f, b0=0.f,b1=0.f,b2=0.f,b3=0.f;
    #pragma unroll 8
    for (int k=0;k<64;k++){
      float a = A[rr][k];
      float4 w1 = *(const float4*)&W1[k*64 + cg*4];
      float4 w2 = *(const float4*)&W2[k*64 + cg*4];
      a0 = fmaf(a, w1.x, a0); a1 = fmaf(a, w1.y, a1); a2 = fmaf(a, w1.z, a2); a3 = fmaf(a, w1.w, a3);
      b0 = fmaf(a, w2.x, b0); b1 = fmaf(a, w2.y, b1); b2 = fmaf(a, w2.z, b2); b3 = fmaf(a, w2.w, b3);
    }
    if (r < nrows){
      *(float4*)&nm[(size_t)r*64 + cg*4]     = make_float4(a0,a1,a2,a3);
      *(float4*)&inner1[(size_t)r*64 + cg*4] = make_float4(b0,b1,b2,b3);
    }
  }
}

// B: hq = he@Wa for rows [0,H), smbuf = sema@Wm for rows [H, H+NS)
__global__ __launch_bounds__(256) void k_rowmatB(const float* __restrict__ he, const float* __restrict__ sema,
    const float* __restrict__ Wa, const float* __restrict__ Wm,
    float* __restrict__ hq, float* __restrict__ smbuf, int H, int NS_){
  __shared__ float W1[4096], W2[4096];
  __shared__ float A[16][65];
  int t = threadIdx.x;
  for (int i=t;i<1024;i+=256){ ((float4*)W1)[i] = ((const float4*)Wa)[i]; ((float4*)W2)[i] = ((const float4*)Wm)[i]; }
  int nrows = H + NS_;
  int ntiles = (nrows + 15) >> 4;
  int rr = t >> 4, cg = t & 15;
  for (int tile = blockIdx.x; tile < ntiles; tile += gridDim.x){
    __syncthreads();
    int r = tile*16 + rr;
    if (r < nrows){
      const float* src = (r < H) ? &he[(size_t)r*64] : &sema[(size_t)(r-H)*64];
      float4 v = *(const float4*)&src[cg*4];
      A[rr][cg*4+0]=v.x; A[rr][cg*4+1]=v.y; A[rr][cg*4+2]=v.z; A[rr][cg*4+3]=v.w;
    }
    __syncthreads();
    const float* Wl = (r < H) ? W1 : W2;
    float a0=0.f,a1=0.f,a2=0.f,a3=0.f;
    #pragma unroll 8
    for (int k=0;k<64;k++){
      float a = A[rr][k];
      float4 w4 = *(const float4*)&Wl[k*64 + cg*4];
      a0 = fmaf(a, w4.x, a0); a1 = fmaf(a, w4.y, a1); a2 = fmaf(a, w4.z, a2); a3 = fmaf(a, w4.w, a3);
    }
    if (r < nrows){
      float4 o = make_float4(a0,a1,a2,a3);
      if (r < H) *(float4*)&hq[(size_t)r*64 + cg*4] = o;
      else       *(float4*)&smbuf[(size_t)(r-H)*64 + cg*4] = o;
    }
  }
}

// ---------------- attention + W_upd matvec fused; persistent grid ----------------
__global__ __launch_bounds__(256) void k_attn_upd(const int* __restrict__ off_hed, const unsigned* __restrict__ edge_hed,
    const float* __restrict__ nm_c, const float* __restrict__ smb, const float* __restrict__ hq,
    const float* __restrict__ W, const float* __restrict__ he_cur, float* __restrict__ he_next, int H){
  __shared__ float Wl[4096];
  __shared__ float sm_lds[640];
  __shared__ float aggl[256];
  int t = threadIdx.x;
  for (int i=t;i<1024;i+=256) ((float4*)Wl)[i] = ((const float4*)W)[i];
  for (int i=t;i<640;i+=256) sm_lds[i] = smb[i];
  __syncthreads();
  int w = t >> 6, lane = t & 63;
  int nhb = (H + 3) >> 2;
  for (int hb = blockIdx.x; hb < nhb; hb += gridDim.x){
    int h = hb*4 + w;
    if (h >= H) continue;
    int start = off_hed[h], end = off_hed[h+1];
    if (start == end){
      he_next[(size_t)h*64 + lane] = he_cur[(size_t)h*64 + lane];
      continue;
    }
    int g = lane >> 4, dl = (lane & 15)*4;
    float4 q4 = *(const float4*)&hq[(size_t)h*64 + dl];
    float ax=0.f, ay=0.f, az=0.f, aw=0.f, dsum=0.f, m=-3.4e38f;
    for (int idx0 = start; idx0 < end; idx0 += 4){
      int idx = idx0 + g;
      bool valid = idx < end;
      unsigned u = valid ? edge_hed[idx] : 0u;
      int slot = u & 0xFFFFF, sem = u >> 20;
      float4 nm4 = make_float4(0.f,0.f,0.f,0.f);
      if (valid) nm4 = *(const float4*)&nm_c[(size_t)slot*64 + dl];
      float4 sm4 = *(const float4*)&sm_lds[sem*64 + dl];
      float mkx = nm4.x+sm4.x, mky = nm4.y+sm4.y, mkz = nm4.z+sm4.z, mkw = nm4.w+sm4.w;
      float part = mkx*q4.x + mky*q4.y + mkz*q4.z + mkw*q4.w;
      part = group16_sum(part);
      float l = valid ? part : -3.4e38f;
      float mn = fmaxf(m, l);
      float scale = __expf(m - mn);
      float wgt = valid ? __expf(l - mn) : 0.f;
      ax = ax*scale + wgt*mkx; ay = ay*scale + wgt*mky;
      az = az*scale + wgt*mkz; aw = aw*scale + wgt*mkw;
      dsum = dsum*scale + wgt;
      m = mn;
    }
    float mg = fmaxf(m, __shfl_xor(m, 16, 64));
    mg = fmaxf(mg, __shfl_xor(mg, 32, 64));
    float cs = __expf(m - mg);
    ax*=cs; ay*=cs; az*=cs; aw*=cs; dsum*=cs;
    ax = xgroup_sum(ax); ay = xgroup_sum(ay); az = xgroup_sum(az); aw = xgroup_sum(aw);
    dsum = xgroup_sum(dsum);
    if (lane < 16){
      float inv = 1.f/(dsum + EPSF);
      aggl[w*64 + dl+0] = ax*inv;
      aggl[w*64 + dl+1] = ay*inv;
      aggl[w*64 + dl+2] = az*inv;
      aggl[w*64 + dl+3] = aw*inv;
    }
    float o = 0.f;
    #pragma unroll 8
    for (int j=0;j<64;j++) o = fmaf(aggl[w*64 + j], Wl[j*64 + lane], o);
    he_next[(size_t)h*64 + lane] = tanhf(o);
  }
}

// ---------------- per-member-slot aggregation; persistent grid ----------------
__global__ __launch_bounds__(256) void k_nodeagg2(const int* __restrict__ mcountp,
    const int* __restrict__ off_slot, const unsigned* __restrict__ edge_src,
    const float* __restrict__ he_next, const float* __restrict__ sema,
    float* __restrict__ nagg, float* __restrict__ oagg){
  __shared__ float sm_lds[640];
  int t = threadIdx.x;
  for (int i=t;i<640;i+=256) sm_lds[i] = sema[i];
  __syncthreads();
  int w = t >> 6, lane = t & 63;
  int mc = *mcountp;
  int npb = (mc + 3) >> 2;
  int g = lane >> 4, dl = (lane & 15)*4;
  for (int pb = blockIdx.x; pb < npb; pb += gridDim.x){
    int p = pb*4 + w;
    if (p >= mc) continue;
    int start = off_slot[p], end = off_slot[p+1];
    float anx=0.f, any_=0.f, anz=0.f, anw=0.f;
    float aox=0.f, aoy=0.f, aoz=0.f, aow=0.f;
    for (int idx0 = start; idx0 < end; idx0 += 4){
      int idx = idx0 + g;
      if (idx < end){
        unsigned u = edge_src[idx];
        int hd = u & 0xFFFFF, sem = u >> 20;
        float4 hv = *(const float4*)&he_next[(size_t)hd*64 + dl];
        float4 sv = *(const float4*)&sm_lds[sem*64 + dl];
        anx += hv.x; any_ += hv.y; anz += hv.z; anw += hv.w;
        aox = fmaf(hv.x, sv.x, aox); aoy = fmaf(hv.y, sv.y, aoy);
        aoz = fmaf(hv.z, sv.z, aoz); aow = fmaf(hv.w, sv.w, aow);
      }
    }
    anx = xgroup_sum(anx); any_ = xgroup_sum(any_); anz = xgroup_sum(anz); anw = xgroup_sum(anw);
    aox = xgroup_sum(aox); aoy = xgroup_sum(aoy); aoz = xgroup_sum(aoz); aow = xgroup_sum(aow);
    if (lane < 16){
      float inv = 1.f/((float)(end - start) + EPSF);
      *(float4*)&nagg[(size_t)p*64 + dl] = make_float4(anx*inv, any_*inv, anz*inv, anw*inv);
      *(float4*)&oagg[(size_t)p*64 + dl] = make_float4(aox*inv, aoy*inv, aoz*inv, aow*inv);
    }
  }
}

// ---------------- fused mat2+mat3, W from L1/L2 (only A tiles in LDS) ----------------
// inner = leaky(inner1 + nagg@Wi2); ne[mlist] = tanh(inner@Wn + oagg@We + nagg@Ws)
__global__ __launch_bounds__(256) void k_matfuse(const float* __restrict__ inner1, const float* __restrict__ nagg,
    const float* __restrict__ oagg, const float* __restrict__ Wi2, const float* __restrict__ Wn,
    const float* __restrict__ We, const float* __restrict__ Ws,
    const int* __restrict__ mlist, const int* __restrict__ mcountp, float* __restrict__ ne){
  __shared__ float Ai[16][65], An[16][65], Ao[16][65];
  int t = threadIdx.x;
  int cnt = *mcountp;
  int ntiles = (cnt + 15) >> 4;
  int rr = t >> 4, cg = t & 15;
  for (int tile = blockIdx.x; tile < ntiles; tile += gridDim.x){
    __syncthreads();
    int r = tile*16 + rr;
    if (r < cnt){
      float4 v = *(const float4*)&inner1[(size_t)r*64 + cg*4];
      Ai[rr][cg*4+0]=v.x; Ai[rr][cg*4+1]=v.y; Ai[rr][cg*4+2]=v.z; Ai[rr][cg*4+3]=v.w;
      float4 u = *(const float4*)&nagg[(size_t)r*64 + cg*4];
      An[rr][cg*4+0]=u.x; An[rr][cg*4+1]=u.y; An[rr][cg*4+2]=u.z; An[rr][cg*4+3]=u.w;
      float4 z = *(const float4*)&oagg[(size_t)r*64 + cg*4];
      Ao[rr][cg*4+0]=z.x; Ao[rr][cg*4+1]=z.y; Ao[rr][cg*4+2]=z.z; Ao[rr][cg*4+3]=z.w;
    }
    __syncthreads();
    // phase 1: inner = leaky(inner1 + nagg@Wi2); W from global (L1/L2-resident)
    float a0=0.f,a1=0.f,a2=0.f,a3=0.f;
    #pragma unroll 8
    for (int k=0;k<64;k++){
      float x = An[rr][k];
      float4 w4 = *(const float4*)&Wi2[k*64 + cg*4];
      a0 = fmaf(x, w4.x, a0); a1 = fmaf(x, w4.y, a1); a2 = fmaf(x, w4.z, a2); a3 = fmaf(x, w4.w, a3);
    }
    a0 += Ai[rr][cg*4+0]; a1 += Ai[rr][cg*4+1]; a2 += Ai[rr][cg*4+2]; a3 += Ai[rr][cg*4+3];
    __syncthreads();   // all phase-1 reads of Ai done before overwrite
    Ai[rr][cg*4+0] = a0 >= 0.f ? a0 : 0.01f*a0;
    Ai[rr][cg*4+1] = a1 >= 0.f ? a1 : 0.01f*a1;
    Ai[rr][cg*4+2] = a2 >= 0.f ? a2 : 0.01f*a2;
    Ai[rr][cg*4+3] = a3 >= 0.f ? a3 : 0.01f*a3;
    __syncthreads();
    // phase 2: out = tanh(inner@Wn + oagg@We + nagg@Ws)
    float b0=0.f,b1=0.f,b2=0.f,b3=0.f;
    #pragma unroll 4
    for (int k=0;k<64;k++){
      float x1 = Ai[rr][k], x2 = Ao[rr][k], x3 = An[rr][k];
      float4 w1 = *(const float4*)&Wn[k*64 + cg*4];
      float4 w2 = *(const float4*)&We[k*64 + cg*4];
      float4 w3 = *(const float4*)&Ws[k*64 + cg*4];
      b0 += x1*w1.x + x2*w2.x + x3*w3.x;
      b1 += x1*w1.y + x2*w2.y + x3*w3.y;
      b2 += x1*w1.z + x2*w2.z + x3*w3.z;
      b3 += x1*w1.w + x2*w2.w + x3*w3.w;
    }
    if (r < cnt){
      float4 o = make_float4(tanhf(b0), tanhf(b1), tanhf(b2), tanhf(b3));
      *(float4*)&ne[(size_t)mlist[r]*64 + cg*4] = o;
    }
  }
}

extern "C" void kernel_launch(void* const* d_in, const int* in_sizes, int n_in,
                              void* d_out, int out_size, void* d_ws, size_t ws_size,
                              hipStream_t stream)
{
  (void)in_sizes; (void)n_in; (void)out_size; (void)ws_size;
  const float* node_emb  = (const float*)d_in[0];
  const float* hyper_emb = (const float*)d_in[1];
  const float* sema_emb  = (const float*)d_in[2];
  const float* W_msg = (const float*)d_in[3];
  const float* W_att = (const float*)d_in[4];
  const float* W_upd = (const float*)d_in[5];
  const float* Wi1   = (const float*)d_in[6];
  const float* Wi2   = (const float*)d_in[7];
  const float* Wo_n  = (const float*)d_in[8];
  const float* Wo_e  = (const float*)d_in[9];
  const float* Wo_s  = (const float*)d_in[10];
  const int* node_indices = (const int*)d_in[11];
  const int* semalinks    = (const int*)d_in[14];

  constexpr int N = 100000, H = 20000, NS = 10, L = 2, E = 1000000, NB = 50000;

  float* out_ne = (float*)d_out;                    // N*64
  float* out_he = (float*)d_out + (size_t)N*64;     // H*64

  char* wsp = (char*)d_ws;
  auto alloc = [&](size_t bytes)->char*{ char* p = wsp; wsp += (bytes + 255) & ~(size_t)255; return p; };
  // contiguous zero-block: member, cnt_hed, cnt_slot, cur_hed, cur_slot, mcount
  char* zstart = wsp;
  int* member   = (int*)alloc((size_t)N*4);
  int* cnt_hed  = (int*)alloc((size_t)H*4);
  int* cnt_slot = (int*)alloc((size_t)NSLOT*4);
  int* cur_hed  = (int*)alloc((size_t)H*4);
  int* cur_slot = (int*)alloc((size_t)NSLOT*4);
  int* mcount   = (int*)alloc(256);
  size_t zbytes = (size_t)(wsp - zstart);
  int* off_hed   = (int*)alloc((size_t)(H+1)*4);
  int* off_slot  = (int*)alloc((size_t)(NSLOT+1)*4);
  int* mlist     = (int*)alloc((size_t)NB*4);
  int* partials  = (int*)alloc(256);
  ull* rec       = (ull*)alloc((size_t)E*8);
  unsigned* edge_hed = (unsigned*)alloc((size_t)E*4);
  unsigned* edge_src = (unsigned*)alloc((size_t)E*4);
  float* smbuf  = (float*)alloc((size_t)NS*64*4);
  float* hq     = (float*)alloc((size_t)H*64*4);
  float* nm_c   = (float*)alloc((size_t)NB*64*4);
  float* he1    = (float*)alloc((size_t)H*64*4);
  float* naggb  = (float*)alloc((size_t)NB*64*4);
  float* oaggb  = (float*)alloc((size_t)NB*64*4);
  float* inner1 = (float*)alloc((size_t)NB*64*4);

  hipMemsetAsync(zstart, 0, zbytes, stream);

  k_copy4<<<(N*64/4 + 255)/256, 256, 0, stream>>>((const float4*)node_emb, (float4*)out_ne, N*64/4);
  k_set_member<<<(NB+255)/256, 256, 0, stream>>>(node_indices, member, NB);
  k_build_list<<<(N+255)/256, 256, 0, stream>>>(member, mlist, mcount, N);
  k_rec<<<(E+255)/256, 256, 0, stream>>>(semalinks, member, rec, E);
  k_wcount<<<1024, 256, 0, stream>>>(rec, mcount, cnt_hed, cnt_slot, E);

  int nb_h = (H + 2047)/2048, nb_s = (NSLOT + 2047)/2048;
  k_scan1<<<nb_h, 256, 0, stream>>>(cnt_hed, off_hed, H, partials);
  k_scan2<<<1, 64, 0, stream>>>(partials, nb_h, off_hed, H);
  k_scan3<<<(H+255)/256, 256, 0, stream>>>(off_hed, partials, H);
  k_scan1<<<nb_s, 256, 0, stream>>>(cnt_slot, off_slot, NSLOT, partials);
  k_scan2<<<1, 64, 0, stream>>>(partials, nb_s, off_slot, NSLOT);
  k_scan3<<<(NSLOT+255)/256, 256, 0, stream>>>(off_slot, partials, NSLOT);

  k_scatter2<0><<<1024, 256, 0, stream>>>(rec, mcount, off_hed,  cur_hed,  edge_hed, E);
  k_scatter2<1><<<1024, 256, 0, stream>>>(rec, mcount, off_slot, cur_slot, edge_src, E);

  for (int i = 0; i < L; ++i){
    const float* Wm = W_msg + (size_t)i*4096;
    const float* Wa = W_att + (size_t)i*4096;
    const float* Wu = W_upd + (size_t)i*4096;
    const float* wi1 = Wi1 + (size_t)i*4096;
    const float* wi2 = Wi2 + (size_t)i*4096;
    const float* won = Wo_n + (size_t)i*4096;
    const float* woe = Wo_e + (size_t)i*4096;
    const float* wos = Wo_s + (size_t)i*4096;
    const float* he_cur = (i == 0) ? hyper_emb : he1;
    float* he_next = (i == 0) ? he1 : out_he;

    k_rowmatA<<<512, 256, 0, stream>>>(out_ne, Wm, wi1, mlist, mcount, nm_c, inner1);
    k_rowmatB<<<512, 256, 0, stream>>>(he_cur, sema_emb, Wa, Wm, hq, smbuf, H, NS);
    k_attn_upd<<<1280, 256, 0, stream>>>(off_hed, edge_hed, nm_c, smbuf, hq, Wu, he_cur, he_next, H);
    k_nodeagg2<<<1280, 256, 0, stream>>>(mcount, off_slot, edge_src, he_next, sema_emb, naggb, oaggb);
    k_matfuse<<<2048, 256, 0, stream>>>(inner1, naggb, oaggb, wi2, won, woe, wos, mlist, mcount, out_ne);
  }
}

// Round 9
// 482.904 us; speedup vs baseline: 1.0072x; 1.0072x over previous
//
#include <hip/hip_runtime.h>
#include <cmath>

// HyperKGL: N=100000, H=20000, NS=10, D=64, L=2, E=1e6, NB=50000
// R8 -> R9: register-blocked GEMM64 (4 rows x 4 cols per thread, A staged
// TRANSPOSED in LDS so one ds_read_b128 feeds 4 rows; one W float4 feeds 16
// FMAs). W back in LDS (R8 showed global-W thrashes L1). matfuse split into
// K1/K2/K3 to keep LDS <= 66KB (2-4 blocks/CU). Same blocking in rowmatA/B.

#define EPSF 1e-9f
#define NSLOT 40960
#define SENT 0xFFFFFFFFu
typedef unsigned long long ull;

__device__ __forceinline__ float group16_sum(float v){
  v += __shfl_xor(v, 1, 64);
  v += __shfl_xor(v, 2, 64);
  v += __shfl_xor(v, 4, 64);
  v += __shfl_xor(v, 8, 64);
  return v;
}
__device__ __forceinline__ float xgroup_sum(float v){
  v += __shfl_xor(v, 16, 64);
  v += __shfl_xor(v, 32, 64);
  return v;
}

// ---------------- setup ----------------
__global__ __launch_bounds__(256) void k_copy4(const float4* __restrict__ in, float4* __restrict__ out, int n){
  int i = blockIdx.x*256 + threadIdx.x;
  if (i < n) out[i] = in[i];
}

__global__ __launch_bounds__(256) void k_set_member(const int* __restrict__ idx, int* __restrict__ member, int n){
  int i = blockIdx.x*256 + threadIdx.x;
  if (i < n) member[idx[i]] = 1;
}

__global__ __launch_bounds__(256) void k_build_list(int* __restrict__ member, int* __restrict__ mlist,
                                                    int* __restrict__ mcount, int N){
  int n = blockIdx.x*256 + threadIdx.x;
  if (n < N && member[n]) {
    int p = atomicAdd(mcount, 1);
    mlist[p] = n;
    member[n] = p + 2;   // slot+2 (0 = non-member)
  }
}

__global__ __launch_bounds__(256) void k_rec(const int* __restrict__ sl, const int* __restrict__ member,
                                             ull* __restrict__ rec, int E){
  int e = blockIdx.x*256 + threadIdx.x;
  if (e >= E) return;
  int src = sl[3*e];
  int m = member[src];
  if (m){
    unsigned lo = (unsigned)(m-2) | ((unsigned)sl[3*e+2] << 20);
    rec[e] = (ull)lo | ((ull)(unsigned)sl[3*e+1] << 32);
  } else {
    rec[e] = (ull)SENT << 32;
  }
}

__global__ __launch_bounds__(256) void k_wcount(const ull* __restrict__ rec, const int* __restrict__ mcountp,
    int* __restrict__ cnt_hed, int* __restrict__ cnt_slot, int E){
  int w = blockIdx.x & 7;
  int chunk = blockIdx.x >> 3;
  int nchunk = gridDim.x >> 3;
  int per = (E + nchunk - 1) / nchunk;
  int lo_i = chunk * per;
  int hi_i = min(E, lo_i + per);
  int divs = (*mcountp + 7) >> 3;
  for (int i = lo_i + threadIdx.x; i < hi_i; i += 256){
    ull r = rec[i];
    unsigned hed = (unsigned)(r >> 32);
    if (hed == SENT) continue;
    int slot = (int)(r & 0xFFFFF);
    if ((int)hed / 2500 == w) atomicAdd(&cnt_hed[hed], 1);
    if (slot / divs   == w) atomicAdd(&cnt_slot[slot], 1);
  }
}

__global__ __launch_bounds__(256) void k_scan1(const int* __restrict__ in, int* __restrict__ out, int n,
                                               int* __restrict__ partials){
  __shared__ int s[256];
  int b = blockIdx.x, t = threadIdx.x;
  int base = b*2048 + t*8;
  int v[8]; int sum = 0;
  #pragma unroll
  for (int j=0;j<8;j++){ int i = base + j; v[j] = (i<n) ? in[i] : 0; sum += v[j]; }
  s[t] = sum;
  __syncthreads();
  for (int o=1;o<256;o<<=1){
    int x = (t>=o) ? s[t-o] : 0;
    __syncthreads();
    s[t] += x;
    __syncthreads();
  }
  int excl = s[t] - sum;
  if (t == 255) partials[b] = s[255];
  int run = excl;
  #pragma unroll
  for (int j=0;j<8;j++){ int i = base + j; if (i<n) out[i] = run; run += v[j]; }
}

__global__ void k_scan2(int* __restrict__ partials, int nb, int* __restrict__ out, int n){
  if (threadIdx.x==0 && blockIdx.x==0){
    int run = 0;
    for (int i=0;i<nb;i++){ int x = partials[i]; partials[i] = run; run += x; }
    out[n] = run;
  }
}

__global__ __launch_bounds__(256) void k_scan3(int* __restrict__ out, const int* __restrict__ partials, int n){
  int i = blockIdx.x*256 + threadIdx.x;
  if (i < n) out[i] += partials[i >> 11];
}

template<int KEY>
__global__ __launch_bounds__(256) void k_scatter2(const ull* __restrict__ rec,
    const int* __restrict__ mcountp,
    const int* __restrict__ off, int* __restrict__ cur, unsigned* __restrict__ dst, int E){
  int w = blockIdx.x & 7;
  int chunk = blockIdx.x >> 3;
  int nchunk = gridDim.x >> 3;
  int per = (E + nchunk - 1) / nchunk;
  int lo_i = chunk * per;
  int hi_i = min(E, lo_i + per);
  int div = KEY ? ((*mcountp + 7) >> 3) : 2500;
  for (int i = lo_i + threadIdx.x; i < hi_i; i += 256){
    ull r = rec[i];
    unsigned hed = (unsigned)(r >> 32);
    if (hed == SENT) continue;
    unsigned lo = (unsigned)r;
    int slot = lo & 0xFFFFF;
    int key = KEY ? slot : (int)hed;
    if (key / div != w) continue;
    unsigned payload = KEY ? (hed | (lo & 0xFFF00000u)) : lo;
    int p = off[key] + atomicAdd(&cur[key], 1);
    dst[p] = payload;
  }
}

// ================= register-blocked GEMM64 pieces =================
// Layout: 256 threads; cg = t&15 (4 cols: cg*4..+3); rg = t>>4 (4 rows: rg*4..+3).
// A staged transposed: At[k][row] (pad 65). One tile = 64 rows.

// stage 64 rows of src (row-major, 64 cols) into At; rows >= nrows -> 0
#define STAGE_AT(At, LOADEXPR)                                         \
  {                                                                    \
    int cg_ = threadIdx.x & 15, rl_ = threadIdx.x >> 4;                \
    for (int p_ = 0; p_ < 4; ++p_){                                    \
      int rloc_ = p_*16 + rl_;                                         \
      int r_ = ro + rloc_;                                             \
      float4 v_ = make_float4(0.f,0.f,0.f,0.f);                        \
      if (r_ < nrows){ v_ = (LOADEXPR); }                              \
      At[cg_*4+0][rloc_] = v_.x;                                       \
      At[cg_*4+1][rloc_] = v_.y;                                       \
      At[cg_*4+2][rloc_] = v_.z;                                       \
      At[cg_*4+3][rloc_] = v_.w;                                       \
    }                                                                  \
  }

// acc[i] (i=0..3, row rg*4+i) += At-row-block @ W  (W in LDS, row-major 64x64)
__device__ __forceinline__ void gemm_acc1(const float* __restrict__ Wl, const float (*At)[65],
                                          int rg4, int cg4, float4 acc[4]){
  #pragma unroll 8
  for (int k = 0; k < 64; ++k){
    const float4 w = *(const float4*)&Wl[k*64 + cg4];
    const float4 a = *(const float4*)&At[k][rg4];
    acc[0].x = fmaf(a.x,w.x,acc[0].x); acc[0].y = fmaf(a.x,w.y,acc[0].y);
    acc[0].z = fmaf(a.x,w.z,acc[0].z); acc[0].w = fmaf(a.x,w.w,acc[0].w);
    acc[1].x = fmaf(a.y,w.x,acc[1].x); acc[1].y = fmaf(a.y,w.y,acc[1].y);
    acc[1].z = fmaf(a.y,w.z,acc[1].z); acc[1].w = fmaf(a.y,w.w,acc[1].w);
    acc[2].x = fmaf(a.z,w.x,acc[2].x); acc[2].y = fmaf(a.z,w.y,acc[2].y);
    acc[2].z = fmaf(a.z,w.z,acc[2].z); acc[2].w = fmaf(a.z,w.w,acc[2].w);
    acc[3].x = fmaf(a.w,w.x,acc[3].x); acc[3].y = fmaf(a.w,w.y,acc[3].y);
    acc[3].z = fmaf(a.w,w.z,acc[3].z); acc[3].w = fmaf(a.w,w.w,acc[3].w);
  }
}

// rowmatA: nm = ne[mlist]@Wm ; inner1 = ne[mlist]@Wi1  (one gather, two GEMMs)
__global__ __launch_bounds__(256) void k_rowmatA(const float* __restrict__ ne, const float* __restrict__ Wm,
    const float* __restrict__ Wi1, const int* __restrict__ mlist, const int* __restrict__ mcountp,
    float* __restrict__ nm, float* __restrict__ inner1){
  __shared__ float W1[4096], W2[4096];
  __shared__ float At[64][65];
  int t = threadIdx.x;
  int nrows = *mcountp;
  int ntiles = (nrows + 63) >> 6;
  if ((int)blockIdx.x >= ntiles) return;
  for (int i=t;i<1024;i+=256){ ((float4*)W1)[i] = ((const float4*)Wm)[i]; ((float4*)W2)[i] = ((const float4*)Wi1)[i]; }
  int cg = t & 15, rg = t >> 4;
  int cg4 = cg*4, rg4 = rg*4;
  for (int tile = blockIdx.x; tile < ntiles; tile += gridDim.x){
    int ro = tile << 6;
    __syncthreads();
    STAGE_AT(At, *(const float4*)&ne[(size_t)mlist[r_]*64 + cg_*4])
    __syncthreads();
    float4 a1[4] = {make_float4(0,0,0,0),make_float4(0,0,0,0),make_float4(0,0,0,0),make_float4(0,0,0,0)};
    float4 a2[4] = {make_float4(0,0,0,0),make_float4(0,0,0,0),make_float4(0,0,0,0),make_float4(0,0,0,0)};
    #pragma unroll 4
    for (int k = 0; k < 64; ++k){
      const float4 w1 = *(const float4*)&W1[k*64 + cg4];
      const float4 w2 = *(const float4*)&W2[k*64 + cg4];
      const float4 a  = *(const float4*)&At[k][rg4];
      a1[0].x=fmaf(a.x,w1.x,a1[0].x); a1[0].y=fmaf(a.x,w1.y,a1[0].y); a1[0].z=fmaf(a.x,w1.z,a1[0].z); a1[0].w=fmaf(a.x,w1.w,a1[0].w);
      a1[1].x=fmaf(a.y,w1.x,a1[1].x); a1[1].y=fmaf(a.y,w1.y,a1[1].y); a1[1].z=fmaf(a.y,w1.z,a1[1].z); a1[1].w=fmaf(a.y,w1.w,a1[1].w);
      a1[2].x=fmaf(a.z,w1.x,a1[2].x); a1[2].y=fmaf(a.z,w1.y,a1[2].y); a1[2].z=fmaf(a.z,w1.z,a1[2].z); a1[2].w=fmaf(a.z,w1.w,a1[2].w);
      a1[3].x=fmaf(a.w,w1.x,a1[3].x); a1[3].y=fmaf(a.w,w1.y,a1[3].y); a1[3].z=fmaf(a.w,w1.z,a1[3].z); a1[3].w=fmaf(a.w,w1.w,a1[3].w);
      a2[0].x=fmaf(a.x,w2.x,a2[0].x); a2[0].y=fmaf(a.x,w2.y,a2[0].y); a2[0].z=fmaf(a.x,w2.z,a2[0].z); a2[0].w=fmaf(a.x,w2.w,a2[0].w);
      a2[1].x=fmaf(a.y,w2.x,a2[1].x); a2[1].y=fmaf(a.y,w2.y,a2[1].y); a2[1].z=fmaf(a.y,w2.z,a2[1].z); a2[1].w=fmaf(a.y,w2.w,a2[1].w);
      a2[2].x=fmaf(a.z,w2.x,a2[2].x); a2[2].y=fmaf(a.z,w2.y,a2[2].y); a2[2].z=fmaf(a.z,w2.z,a2[2].z); a2[2].w=fmaf(a.z,w2.w,a2[2].w);
      a2[3].x=fmaf(a.w,w2.x,a2[3].x); a2[3].y=fmaf(a.w,w2.y,a2[3].y); a2[3].z=fmaf(a.w,w2.z,a2[3].z); a2[3].w=fmaf(a.w,w2.w,a2[3].w);
    }
    #pragma unroll
    for (int i = 0; i < 4; ++i){
      int r = ro + rg4 + i;
      if (r < nrows){
        *(float4*)&nm[(size_t)r*64 + cg4]     = a1[i];
        *(float4*)&inner1[(size_t)r*64 + cg4] = a2[i];
      }
    }
  }
}

// rowmatB: hq = he@Wa (tiled); block 0 additionally computes smbuf = sema@Wm (direct)
__global__ __launch_bounds__(256) void k_rowmatB(const float* __restrict__ he, const float* __restrict__ sema,
    const float* __restrict__ Wa, const float* __restrict__ Wm,
    float* __restrict__ hq, float* __restrict__ smbuf, int H, int NS_){
  __shared__ float W1[4096];
  __shared__ float At[64][65];
  int t = threadIdx.x;
  if (blockIdx.x == 0 && t < 160){
    int sr = t >> 4, c4 = (t & 15)*4;
    float4 accs = make_float4(0,0,0,0);
    #pragma unroll 8
    for (int k = 0; k < 64; ++k){
      float a = sema[sr*64 + k];
      float4 w = *(const float4*)&Wm[k*64 + c4];
      accs.x = fmaf(a,w.x,accs.x); accs.y = fmaf(a,w.y,accs.y);
      accs.z = fmaf(a,w.z,accs.z); accs.w = fmaf(a,w.w,accs.w);
    }
    *(float4*)&smbuf[(size_t)sr*64 + c4] = accs;
  }
  int nrows = H;
  int ntiles = (nrows + 63) >> 6;
  if ((int)blockIdx.x >= ntiles) return;
  for (int i=t;i<1024;i+=256) ((float4*)W1)[i] = ((const float4*)Wa)[i];
  int cg = t & 15, rg = t >> 4;
  int cg4 = cg*4, rg4 = rg*4;
  for (int tile = blockIdx.x; tile < ntiles; tile += gridDim.x){
    int ro = tile << 6;
    __syncthreads();
    STAGE_AT(At, *(const float4*)&he[(size_t)r_*64 + cg_*4])
    __syncthreads();
    float4 acc[4] = {make_float4(0,0,0,0),make_float4(0,0,0,0),make_float4(0,0,0,0),make_float4(0,0,0,0)};
    gemm_acc1(W1, At, rg4, cg4, acc);
    #pragma unroll
    for (int i = 0; i < 4; ++i){
      int r = ro + rg4 + i;
      if (r < nrows) *(float4*)&hq[(size_t)r*64 + cg4] = acc[i];
    }
  }
}

// K1: inner1 <- leaky(inner1 + nagg@Wi2)   (in place)
__global__ __launch_bounds__(256) void k_mat2(const float* __restrict__ nagg, const float* __restrict__ Wi2,
    const int* __restrict__ mcountp, float* __restrict__ inner1){
  __shared__ float W1[4096];
  __shared__ float At[64][65];
  int t = threadIdx.x;
  int nrows = *mcountp;
  int ntiles = (nrows + 63) >> 6;
  if ((int)blockIdx.x >= ntiles) return;
  for (int i=t;i<1024;i+=256) ((float4*)W1)[i] = ((const float4*)Wi2)[i];
  int cg = t & 15, rg = t >> 4;
  int cg4 = cg*4, rg4 = rg*4;
  for (int tile = blockIdx.x; tile < ntiles; tile += gridDim.x){
    int ro = tile << 6;
    __syncthreads();
    STAGE_AT(At, *(const float4*)&nagg[(size_t)r_*64 + cg_*4])
    __syncthreads();
    float4 acc[4] = {make_float4(0,0,0,0),make_float4(0,0,0,0),make_float4(0,0,0,0),make_float4(0,0,0,0)};
    gemm_acc1(W1, At, rg4, cg4, acc);
    #pragma unroll
    for (int i = 0; i < 4; ++i){
      int r = ro + rg4 + i;
      if (r < nrows){
        float4 v = *(const float4*)&inner1[(size_t)r*64 + cg4];
        float x0 = acc[i].x + v.x, x1 = acc[i].y + v.y, x2 = acc[i].z + v.z, x3 = acc[i].w + v.w;
        float4 o;
        o.x = x0 >= 0.f ? x0 : 0.01f*x0;
        o.y = x1 >= 0.f ? x1 : 0.01f*x1;
        o.z = x2 >= 0.f ? x2 : 0.01f*x2;
        o.w = x3 >= 0.f ? x3 : 0.01f*x3;
        *(float4*)&inner1[(size_t)r*64 + cg4] = o;
      }
    }
  }
}

// K2: q = oagg@We + nagg@Ws
__global__ __launch_bounds__(256) void k_matq(const float* __restrict__ oagg, const float* __restrict__ nagg,
    const float* __restrict__ We, const float* __restrict__ Ws,
    const int* __restrict__ mcountp, float* __restrict__ q){
  __shared__ float W1[4096], W2[4096];
  __shared__ float At1[64][65], At2[64][65];
  int t = threadIdx.x;
  int nrows = *mcountp;
  int ntiles = (nrows + 63) >> 6;
  if ((int)blockIdx.x >= ntiles) return;
  for (int i=t;i<1024;i+=256){ ((float4*)W1)[i] = ((const float4*)We)[i]; ((float4*)W2)[i] = ((const float4*)Ws)[i]; }
  int cg = t & 15, rg = t >> 4;
  int cg4 = cg*4, rg4 = rg*4;
  for (int tile = blockIdx.x; tile < ntiles; tile += gridDim.x){
    int ro = tile << 6;
    __syncthreads();
    STAGE_AT(At1, *(const float4*)&oagg[(size_t)r_*64 + cg_*4])
    STAGE_AT(At2, *(const float4*)&nagg[(size_t)r_*64 + cg_*4])
    __syncthreads();
    float4 acc[4] = {make_float4(0,0,0,0),make_float4(0,0,0,0),make_float4(0,0,0,0),make_float4(0,0,0,0)};
    #pragma unroll 4
    for (int k = 0; k < 64; ++k){
      const float4 w1 = *(const float4*)&W1[k*64 + cg4];
      const float4 w2 = *(const float4*)&W2[k*64 + cg4];
      const float4 a1 = *(const float4*)&At1[k][rg4];
      const float4 a2 = *(const float4*)&At2[k][rg4];
      acc[0].x += a1.x*w1.x + a2.x*w2.x; acc[0].y += a1.x*w1.y + a2.x*w2.y;
      acc[0].z += a1.x*w1.z + a2.x*w2.z; acc[0].w += a1.x*w1.w + a2.x*w2.w;
      acc[1].x += a1.y*w1.x + a2.y*w2.x; acc[1].y += a1.y*w1.y + a2.y*w2.y;
      acc[1].z += a1.y*w1.z + a2.y*w2.z; acc[1].w += a1.y*w1.w + a2.y*w2.w;
      acc[2].x += a1.z*w1.x + a2.z*w2.x; acc[2].y += a1.z*w1.y + a2.z*w2.y;
      acc[2].z += a1.z*w1.z + a2.z*w2.z; acc[2].w += a1.z*w1.w + a2.z*w2.w;
      acc[3].x += a1.w*w1.x + a2.w*w2.x; acc[3].y += a1.w*w1.y + a2.w*w2.y;
      acc[3].z += a1.w*w1.z + a2.w*w2.z; acc[3].w += a1.w*w1.w + a2.w*w2.w;
    }
    #pragma unroll
    for (int i = 0; i < 4; ++i){
      int r = ro + rg4 + i;
      if (r < nrows) *(float4*)&q[(size_t)r*64 + cg4] = acc[i];
    }
  }
}

// K3: ne[mlist[r]] = tanh(inner1@Wn + q)
__global__ __launch_bounds__(256) void k_mat3f(const float* __restrict__ inner1, const float* __restrict__ q,
    const float* __restrict__ Wn, const int* __restrict__ mlist, const int* __restrict__ mcountp,
    float* __restrict__ ne){
  __shared__ float W1[4096];
  __shared__ float At[64][65];
  int t = threadIdx.x;
  int nrows = *mcountp;
  int ntiles = (nrows + 63) >> 6;
  if ((int)blockIdx.x >= ntiles) return;
  for (int i=t;i<1024;i+=256) ((float4*)W1)[i] = ((const float4*)Wn)[i];
  int cg = t & 15, rg = t >> 4;
  int cg4 = cg*4, rg4 = rg*4;
  for (int tile = blockIdx.x; tile < ntiles; tile += gridDim.x){
    int ro = tile << 6;
    __syncthreads();
    STAGE_AT(At, *(const float4*)&inner1[(size_t)r_*64 + cg_*4])
    __syncthreads();
    float4 acc[4] = {make_float4(0,0,0,0),make_float4(0,0,0,0),make_float4(0,0,0,0),make_float4(0,0,0,0)};
    gemm_acc1(W1, At, rg4, cg4, acc);
    #pragma unroll
    for (int i = 0; i < 4; ++i){
      int r = ro + rg4 + i;
      if (r < nrows){
        float4 v = *(const float4*)&q[(size_t)r*64 + cg4];
        float4 o = make_float4(tanhf(acc[i].x + v.x), tanhf(acc[i].y + v.y),
                               tanhf(acc[i].z + v.z), tanhf(acc[i].w + v.w));
        *(float4*)&ne[(size_t)mlist[r]*64 + cg4] = o;
      }
    }
  }
}

// ---------------- attention + W_upd matvec fused; persistent grid ----------------
__global__ __launch_bounds__(256) void k_attn_upd(const int* __restrict__ off_hed, const unsigned* __restrict__ edge_hed,
    const float* __restrict__ nm_c, const float* __restrict__ smb, const float* __restrict__ hq,
    const float* __restrict__ W, const float* __restrict__ he_cur, float* __restrict__ he_next, int H){
  __shared__ float Wl[4096];
  __shared__ float sm_lds[640];
  __shared__ float aggl[256];
  int t = threadIdx.x;
  for (int i=t;i<1024;i+=256) ((float4*)Wl)[i] = ((const float4*)W)[i];
  for (int i=t;i<640;i+=256) sm_lds[i] = smb[i];
  __syncthreads();
  int w = t >> 6, lane = t & 63;
  int nhb = (H + 3) >> 2;
  for (int hb = blockIdx.x; hb < nhb; hb += gridDim.x){
    int h = hb*4 + w;
    if (h >= H) continue;
    int start = off_hed[h], end = off_hed[h+1];
    if (start == end){
      he_next[(size_t)h*64 + lane] = he_cur[(size_t)h*64 + lane];
      continue;
    }
    int g = lane >> 4, dl = (lane & 15)*4;
    float4 q4 = *(const float4*)&hq[(size_t)h*64 + dl];
    float ax=0.f, ay=0.f, az=0.f, aw=0.f, dsum=0.f, m=-3.4e38f;
    for (int idx0 = start; idx0 < end; idx0 += 4){
      int idx = idx0 + g;
      bool valid = idx < end;
      unsigned u = valid ? edge_hed[idx] : 0u;
      int slot = u & 0xFFFFF, sem = u >> 20;
      float4 nm4 = make_float4(0.f,0.f,0.f,0.f);
      if (valid) nm4 = *(const float4*)&nm_c[(size_t)slot*64 + dl];
      float4 sm4 = *(const float4*)&sm_lds[sem*64 + dl];
      float mkx = nm4.x+sm4.x, mky = nm4.y+sm4.y, mkz = nm4.z+sm4.z, mkw = nm4.w+sm4.w;
      float part = mkx*q4.x + mky*q4.y + mkz*q4.z + mkw*q4.w;
      part = group16_sum(part);
      float l = valid ? part : -3.4e38f;
      float mn = fmaxf(m, l);
      float scale = __expf(m - mn);
      float wgt = valid ? __expf(l - mn) : 0.f;
      ax = ax*scale + wgt*mkx; ay = ay*scale + wgt*mky;
      az = az*scale + wgt*mkz; aw = aw*scale + wgt*mkw;
      dsum = dsum*scale + wgt;
      m = mn;
    }
    float mg = fmaxf(m, __shfl_xor(m, 16, 64));
    mg = fmaxf(mg, __shfl_xor(mg, 32, 64));
    float cs = __expf(m - mg);
    ax*=cs; ay*=cs; az*=cs; aw*=cs; dsum*=cs;
    ax = xgroup_sum(ax); ay = xgroup_sum(ay); az = xgroup_sum(az); aw = xgroup_sum(aw);
    dsum = xgroup_sum(dsum);
    if (lane < 16){
      float inv = 1.f/(dsum + EPSF);
      aggl[w*64 + dl+0] = ax*inv;
      aggl[w*64 + dl+1] = ay*inv;
      aggl[w*64 + dl+2] = az*inv;
      aggl[w*64 + dl+3] = aw*inv;
    }
    float o = 0.f;
    #pragma unroll 8
    for (int j=0;j<64;j++) o = fmaf(aggl[w*64 + j], Wl[j*64 + lane], o);
    he_next[(size_t)h*64 + lane] = tanhf(o);
  }
}

// ---------------- per-member-slot aggregation; persistent grid ----------------
__global__ __launch_bounds__(256) void k_nodeagg2(const int* __restrict__ mcountp,
    const int* __restrict__ off_slot, const unsigned* __restrict__ edge_src,
    const float* __restrict__ he_next, const float* __restrict__ sema,
    float* __restrict__ nagg, float* __restrict__ oagg){
  __shared__ float sm_lds[640];
  int t = threadIdx.x;
  for (int i=t;i<640;i+=256) sm_lds[i] = sema[i];
  __syncthreads();
  int w = t >> 6, lane = t & 63;
  int mc = *mcountp;
  int npb = (mc + 3) >> 2;
  int g = lane >> 4, dl = (lane & 15)*4;
  for (int pb = blockIdx.x; pb < npb; pb += gridDim.x){
    int p = pb*4 + w;
    if (p >= mc) continue;
    int start = off_slot[p], end = off_slot[p+1];
    float anx=0.f, any_=0.f, anz=0.f, anw=0.f;
    float aox=0.f, aoy=0.f, aoz=0.f, aow=0.f;
    for (int idx0 = start; idx0 < end; idx0 += 4){
      int idx = idx0 + g;
      if (idx < end){
        unsigned u = edge_src[idx];
        int hd = u & 0xFFFFF, sem = u >> 20;
        float4 hv = *(const float4*)&he_next[(size_t)hd*64 + dl];
        float4 sv = *(const float4*)&sm_lds[sem*64 + dl];
        anx += hv.x; any_ += hv.y; anz += hv.z; anw += hv.w;
        aox = fmaf(hv.x, sv.x, aox); aoy = fmaf(hv.y, sv.y, aoy);
        aoz = fmaf(hv.z, sv.z, aoz); aow = fmaf(hv.w, sv.w, aow);
      }
    }
    anx = xgroup_sum(anx); any_ = xgroup_sum(any_); anz = xgroup_sum(anz); anw = xgroup_sum(anw);
    aox = xgroup_sum(aox); aoy = xgroup_sum(aoy); aoz = xgroup_sum(aoz); aow = xgroup_sum(aow);
    if (lane < 16){
      float inv = 1.f/((float)(end - start) + EPSF);
      *(float4*)&nagg[(size_t)p*64 + dl] = make_float4(anx*inv, any_*inv, anz*inv, anw*inv);
      *(float4*)&oagg[(size_t)p*64 + dl] = make_float4(aox*inv, aoy*inv, aoz*inv, aow*inv);
    }
  }
}

extern "C" void kernel_launch(void* const* d_in, const int* in_sizes, int n_in,
                              void* d_out, int out_size, void* d_ws, size_t ws_size,
                              hipStream_t stream)
{
  (void)in_sizes; (void)n_in; (void)out_size; (void)ws_size;
  const float* node_emb  = (const float*)d_in[0];
  const float* hyper_emb = (const float*)d_in[1];
  const float* sema_emb  = (const float*)d_in[2];
  const float* W_msg = (const float*)d_in[3];
  const float* W_att = (const float*)d_in[4];
  const float* W_upd = (const float*)d_in[5];
  const float* Wi1   = (const float*)d_in[6];
  const float* Wi2   = (const float*)d_in[7];
  const float* Wo_n  = (const float*)d_in[8];
  const float* Wo_e  = (const float*)d_in[9];
  const float* Wo_s  = (const float*)d_in[10];
  const int* node_indices = (const int*)d_in[11];
  const int* semalinks    = (const int*)d_in[14];

  constexpr int N = 100000, H = 20000, NS = 10, L = 2, E = 1000000, NB = 50000;

  float* out_ne = (float*)d_out;                    // N*64
  float* out_he = (float*)d_out + (size_t)N*64;     // H*64

  char* wsp = (char*)d_ws;
  auto alloc = [&](size_t bytes)->char*{ char* p = wsp; wsp += (bytes + 255) & ~(size_t)255; return p; };
  char* zstart = wsp;
  int* member   = (int*)alloc((size_t)N*4);
  int* cnt_hed  = (int*)alloc((size_t)H*4);
  int* cnt_slot = (int*)alloc((size_t)NSLOT*4);
  int* cur_hed  = (int*)alloc((size_t)H*4);
  int* cur_slot = (int*)alloc((size_t)NSLOT*4);
  int* mcount   = (int*)alloc(256);
  size_t zbytes = (size_t)(wsp - zstart);
  int* off_hed   = (int*)alloc((size_t)(H+1)*4);
  int* off_slot  = (int*)alloc((size_t)(NSLOT+1)*4);
  int* mlist     = (int*)alloc((size_t)NB*4);
  int* partials  = (int*)alloc(256);
  ull* rec       = (ull*)alloc((size_t)E*8);
  unsigned* edge_hed = (unsigned*)alloc((size_t)E*4);
  unsigned* edge_src = (unsigned*)alloc((size_t)E*4);
  float* smbuf  = (float*)alloc((size_t)NS*64*4);
  float* hq     = (float*)alloc((size_t)H*64*4);
  float* nm_c   = (float*)alloc((size_t)NB*64*4);
  float* he1    = (float*)alloc((size_t)H*64*4);
  float* naggb  = (float*)alloc((size_t)NB*64*4);
  float* oaggb  = (float*)alloc((size_t)NB*64*4);
  float* inner1 = (float*)alloc((size_t)NB*64*4);
  float* qb     = (float*)alloc((size_t)NB*64*4);

  hipMemsetAsync(zstart, 0, zbytes, stream);

  k_copy4<<<(N*64/4 + 255)/256, 256, 0, stream>>>((const float4*)node_emb, (float4*)out_ne, N*64/4);
  k_set_member<<<(NB+255)/256, 256, 0, stream>>>(node_indices, member, NB);
  k_build_list<<<(N+255)/256, 256, 0, stream>>>(member, mlist, mcount, N);
  k_rec<<<(E+255)/256, 256, 0, stream>>>(semalinks, member, rec, E);
  k_wcount<<<1024, 256, 0, stream>>>(rec, mcount, cnt_hed, cnt_slot, E);

  int nb_h = (H + 2047)/2048, nb_s = (NSLOT + 2047)/2048;
  k_scan1<<<nb_h, 256, 0, stream>>>(cnt_hed, off_hed, H, partials);
  k_scan2<<<1, 64, 0, stream>>>(partials, nb_h, off_hed, H);
  k_scan3<<<(H+255)/256, 256, 0, stream>>>(off_hed, partials, H);
  k_scan1<<<nb_s, 256, 0, stream>>>(cnt_slot, off_slot, NSLOT, partials);
  k_scan2<<<1, 64, 0, stream>>>(partials, nb_s, off_slot, NSLOT);
  k_scan3<<<(NSLOT+255)/256, 256, 0, stream>>>(off_slot, partials, NSLOT);

  k_scatter2<0><<<1024, 256, 0, stream>>>(rec, mcount, off_hed,  cur_hed,  edge_hed, E);
  k_scatter2<1><<<1024, 256, 0, stream>>>(rec, mcount, off_slot, cur_slot, edge_src, E);

  for (int i = 0; i < L; ++i){
    const float* Wm = W_msg + (size_t)i*4096;
    const float* Wa = W_att + (size_t)i*4096;
    const float* Wu = W_upd + (size_t)i*4096;
    const float* wi1 = Wi1 + (size_t)i*4096;
    const float* wi2 = Wi2 + (size_t)i*4096;
    const float* won = Wo_n + (size_t)i*4096;
    const float* woe = Wo_e + (size_t)i*4096;
    const float* wos = Wo_s + (size_t)i*4096;
    const float* he_cur = (i == 0) ? hyper_emb : he1;
    float* he_next = (i == 0) ? he1 : out_he;

    k_rowmatA<<<640, 256, 0, stream>>>(out_ne, Wm, wi1, mlist, mcount, nm_c, inner1);
    k_rowmatB<<<320, 256, 0, stream>>>(he_cur, sema_emb, Wa, Wm, hq, smbuf, H, NS);
    k_attn_upd<<<1280, 256, 0, stream>>>(off_hed, edge_hed, nm_c, smbuf, hq, Wu, he_cur, he_next, H);
    k_nodeagg2<<<1280, 256, 0, stream>>>(mcount, off_slot, edge_src, he_next, sema_emb, naggb, oaggb);
    k_mat2<<<640, 256, 0, stream>>>(naggb, wi2, mcount, inner1);
    k_matq<<<640, 256, 0, stream>>>(oaggb, naggb, woe, wos, mcount, qb);
    k_mat3f<<<640, 256, 0, stream>>>(inner1, qb, won, mlist, mcount, out_ne);
  }
}

// Round 10
// 420.367 us; speedup vs baseline: 1.1570x; 1.1488x over previous
//
#include <hip/hip_runtime.h>
#include <cmath>

// HyperKGL: N=100000, H=20000, NS=10, D=64, L=2, E=1e6, NB=50000
// R9 -> R10: base = R7 (best, 414us). Single change: sequential-W staging.
// matfuse keeps ONE 16KB W LDS buffer reloaded per phase (Wi2->Wn->We->Ws):
// LDS 78KB->29KB, 2->5 blocks/CU. rowmatA same (Wm->Wi1): 36->20.6KB.
// rowmatB stages only Wa; sema@Wm handled by block-0 prologue.

#define EPSF 1e-9f
#define NSLOT 40960
#define SENT 0xFFFFFFFFu
typedef unsigned long long ull;

__device__ __forceinline__ float group16_sum(float v){
  v += __shfl_xor(v, 1, 64);
  v += __shfl_xor(v, 2, 64);
  v += __shfl_xor(v, 4, 64);
  v += __shfl_xor(v, 8, 64);
  return v;
}
__device__ __forceinline__ float xgroup_sum(float v){
  v += __shfl_xor(v, 16, 64);
  v += __shfl_xor(v, 32, 64);
  return v;
}

// ---------------- setup ----------------
__global__ __launch_bounds__(256) void k_copy4(const float4* __restrict__ in, float4* __restrict__ out, int n){
  int i = blockIdx.x*256 + threadIdx.x;
  if (i < n) out[i] = in[i];
}

__global__ __launch_bounds__(256) void k_set_member(const int* __restrict__ idx, int* __restrict__ member, int n){
  int i = blockIdx.x*256 + threadIdx.x;
  if (i < n) member[idx[i]] = 1;
}

__global__ __launch_bounds__(256) void k_build_list(int* __restrict__ member, int* __restrict__ mlist,
                                                    int* __restrict__ mcount, int N){
  int n = blockIdx.x*256 + threadIdx.x;
  if (n < N && member[n]) {
    int p = atomicAdd(mcount, 1);
    mlist[p] = n;
    member[n] = p + 2;   // slot+2 (0 = non-member)
  }
}

__global__ __launch_bounds__(256) void k_rec(const int* __restrict__ sl, const int* __restrict__ member,
                                             ull* __restrict__ rec, int E){
  int e = blockIdx.x*256 + threadIdx.x;
  if (e >= E) return;
  int src = sl[3*e];
  int m = member[src];
  if (m){
    unsigned lo = (unsigned)(m-2) | ((unsigned)sl[3*e+2] << 20);
    rec[e] = (ull)lo | ((ull)(unsigned)sl[3*e+1] << 32);
  } else {
    rec[e] = (ull)SENT << 32;
  }
}

__global__ __launch_bounds__(256) void k_wcount(const ull* __restrict__ rec, const int* __restrict__ mcountp,
    int* __restrict__ cnt_hed, int* __restrict__ cnt_slot, int E){
  int w = blockIdx.x & 7;
  int chunk = blockIdx.x >> 3;
  int nchunk = gridDim.x >> 3;
  int per = (E + nchunk - 1) / nchunk;
  int lo_i = chunk * per;
  int hi_i = min(E, lo_i + per);
  int divs = (*mcountp + 7) >> 3;
  for (int i = lo_i + threadIdx.x; i < hi_i; i += 256){
    ull r = rec[i];
    unsigned hed = (unsigned)(r >> 32);
    if (hed == SENT) continue;
    int slot = (int)(r & 0xFFFFF);
    if ((int)hed / 2500 == w) atomicAdd(&cnt_hed[hed], 1);
    if (slot / divs   == w) atomicAdd(&cnt_slot[slot], 1);
  }
}

__global__ __launch_bounds__(256) void k_scan1(const int* __restrict__ in, int* __restrict__ out, int n,
                                               int* __restrict__ partials){
  __shared__ int s[256];
  int b = blockIdx.x, t = threadIdx.x;
  int base = b*2048 + t*8;
  int v[8]; int sum = 0;
  #pragma unroll
  for (int j=0;j<8;j++){ int i = base + j; v[j] = (i<n) ? in[i] : 0; sum += v[j]; }
  s[t] = sum;
  __syncthreads();
  for (int o=1;o<256;o<<=1){
    int x = (t>=o) ? s[t-o] : 0;
    __syncthreads();
    s[t] += x;
    __syncthreads();
  }
  int excl = s[t] - sum;
  if (t == 255) partials[b] = s[255];
  int run = excl;
  #pragma unroll
  for (int j=0;j<8;j++){ int i = base + j; if (i<n) out[i] = run; run += v[j]; }
}

__global__ void k_scan2(int* __restrict__ partials, int nb, int* __restrict__ out, int n){
  if (threadIdx.x==0 && blockIdx.x==0){
    int run = 0;
    for (int i=0;i<nb;i++){ int x = partials[i]; partials[i] = run; run += x; }
    out[n] = run;
  }
}

__global__ __launch_bounds__(256) void k_scan3(int* __restrict__ out, const int* __restrict__ partials, int n){
  int i = blockIdx.x*256 + threadIdx.x;
  if (i < n) out[i] += partials[i >> 11];
}

template<int KEY>
__global__ __launch_bounds__(256) void k_scatter2(const ull* __restrict__ rec,
    const int* __restrict__ mcountp,
    const int* __restrict__ off, int* __restrict__ cur, unsigned* __restrict__ dst, int E){
  int w = blockIdx.x & 7;
  int chunk = blockIdx.x >> 3;
  int nchunk = gridDim.x >> 3;
  int per = (E + nchunk - 1) / nchunk;
  int lo_i = chunk * per;
  int hi_i = min(E, lo_i + per);
  int div = KEY ? ((*mcountp + 7) >> 3) : 2500;
  for (int i = lo_i + threadIdx.x; i < hi_i; i += 256){
    ull r = rec[i];
    unsigned hed = (unsigned)(r >> 32);
    if (hed == SENT) continue;
    unsigned lo = (unsigned)r;
    int slot = lo & 0xFFFFF;
    int key = KEY ? slot : (int)hed;
    if (key / div != w) continue;
    unsigned payload = KEY ? (hed | (lo & 0xFFF00000u)) : lo;
    int p = off[key] + atomicAdd(&cur[key], 1);
    dst[p] = payload;
  }
}

// ---------------- 16-row GEMV helper: acc(cols cg4..cg4+3) = A-row rr @ Wl ----------------
__device__ __forceinline__ float4 gemv16(const float* __restrict__ Wl, const float (*A)[65],
                                         int rr, int cg4){
  float a0=0.f,a1=0.f,a2=0.f,a3=0.f;
  #pragma unroll 8
  for (int k=0;k<64;k++){
    float a = A[rr][k];
    float4 w4 = *(const float4*)&Wl[k*64 + cg4];
    a0 = fmaf(a, w4.x, a0); a1 = fmaf(a, w4.y, a1);
    a2 = fmaf(a, w4.z, a2); a3 = fmaf(a, w4.w, a3);
  }
  return make_float4(a0,a1,a2,a3);
}

#define LOAD_W(Wl, Wsrc) for (int i_=threadIdx.x; i_<1024; i_+=256) ((float4*)Wl)[i_] = ((const float4*)(Wsrc))[i_];

// rowmatA: nm = ne[mlist]@Wm ; inner1 = ne[mlist]@Wi1 (one gather, sequential W)
__global__ __launch_bounds__(256) void k_rowmatA(const float* __restrict__ ne, const float* __restrict__ Wm,
    const float* __restrict__ Wi1, const int* __restrict__ mlist, const int* __restrict__ mcountp,
    float* __restrict__ nm, float* __restrict__ inner1){
  __shared__ float Wl[4096];
  __shared__ float A[16][65];
  int t = threadIdx.x;
  int nrows = *mcountp;
  int ntiles = (nrows + 15) >> 4;
  int rr = t >> 4, cg = t & 15;
  int cg4 = cg*4;
  for (int tile = blockIdx.x; tile < ntiles; tile += gridDim.x){
    __syncthreads();
    int r = tile*16 + rr;
    if (r < nrows){
      float4 v = *(const float4*)&ne[(size_t)mlist[r]*64 + cg4];
      A[rr][cg4+0]=v.x; A[rr][cg4+1]=v.y; A[rr][cg4+2]=v.z; A[rr][cg4+3]=v.w;
    }
    LOAD_W(Wl, Wm)
    __syncthreads();
    float4 o1 = gemv16(Wl, A, rr, cg4);
    if (r < nrows) *(float4*)&nm[(size_t)r*64 + cg4] = o1;
    __syncthreads();
    LOAD_W(Wl, Wi1)
    __syncthreads();
    float4 o2 = gemv16(Wl, A, rr, cg4);
    if (r < nrows) *(float4*)&inner1[(size_t)r*64 + cg4] = o2;
  }
}

// rowmatB: hq = he@Wa (only Wa staged); block 0 prologue computes smbuf = sema@Wm
__global__ __launch_bounds__(256) void k_rowmatB(const float* __restrict__ he, const float* __restrict__ sema,
    const float* __restrict__ Wa, const float* __restrict__ Wm,
    float* __restrict__ hq, float* __restrict__ smbuf, int H, int NS_){
  __shared__ float Wl[4096];
  __shared__ float A[16][65];
  int t = threadIdx.x;
  if (blockIdx.x == 0 && t < 160){
    int sr = t >> 4, c4 = (t & 15)*4;
    float4 accs = make_float4(0,0,0,0);
    #pragma unroll 8
    for (int k = 0; k < 64; ++k){
      float a = sema[sr*64 + k];
      float4 w = *(const float4*)&Wm[k*64 + c4];
      accs.x = fmaf(a,w.x,accs.x); accs.y = fmaf(a,w.y,accs.y);
      accs.z = fmaf(a,w.z,accs.z); accs.w = fmaf(a,w.w,accs.w);
    }
    *(float4*)&smbuf[(size_t)sr*64 + c4] = accs;
  }
  LOAD_W(Wl, Wa)
  int nrows = H;
  int ntiles = (nrows + 15) >> 4;
  int rr = t >> 4, cg = t & 15;
  int cg4 = cg*4;
  for (int tile = blockIdx.x; tile < ntiles; tile += gridDim.x){
    __syncthreads();
    int r = tile*16 + rr;
    if (r < nrows){
      float4 v = *(const float4*)&he[(size_t)r*64 + cg4];
      A[rr][cg4+0]=v.x; A[rr][cg4+1]=v.y; A[rr][cg4+2]=v.z; A[rr][cg4+3]=v.w;
    }
    __syncthreads();
    float4 o = gemv16(Wl, A, rr, cg4);
    if (r < nrows) *(float4*)&hq[(size_t)r*64 + cg4] = o;
  }
}

// ---------------- attention + W_upd matvec fused; persistent grid ----------------
__global__ __launch_bounds__(256) void k_attn_upd(const int* __restrict__ off_hed, const unsigned* __restrict__ edge_hed,
    const float* __restrict__ nm_c, const float* __restrict__ smb, const float* __restrict__ hq,
    const float* __restrict__ W, const float* __restrict__ he_cur, float* __restrict__ he_next, int H){
  __shared__ float Wl[4096];
  __shared__ float sm_lds[640];
  __shared__ float aggl[256];
  int t = threadIdx.x;
  for (int i=t;i<1024;i+=256) ((float4*)Wl)[i] = ((const float4*)W)[i];
  for (int i=t;i<640;i+=256) sm_lds[i] = smb[i];
  __syncthreads();
  int w = t >> 6, lane = t & 63;
  int nhb = (H + 3) >> 2;
  for (int hb = blockIdx.x; hb < nhb; hb += gridDim.x){
    int h = hb*4 + w;
    if (h >= H) continue;
    int start = off_hed[h], end = off_hed[h+1];
    if (start == end){
      he_next[(size_t)h*64 + lane] = he_cur[(size_t)h*64 + lane];
      continue;
    }
    int g = lane >> 4, dl = (lane & 15)*4;
    float4 q4 = *(const float4*)&hq[(size_t)h*64 + dl];
    float ax=0.f, ay=0.f, az=0.f, aw=0.f, dsum=0.f, m=-3.4e38f;
    for (int idx0 = start; idx0 < end; idx0 += 4){
      int idx = idx0 + g;
      bool valid = idx < end;
      unsigned u = valid ? edge_hed[idx] : 0u;
      int slot = u & 0xFFFFF, sem = u >> 20;
      float4 nm4 = make_float4(0.f,0.f,0.f,0.f);
      if (valid) nm4 = *(const float4*)&nm_c[(size_t)slot*64 + dl];
      float4 sm4 = *(const float4*)&sm_lds[sem*64 + dl];
      float mkx = nm4.x+sm4.x, mky = nm4.y+sm4.y, mkz = nm4.z+sm4.z, mkw = nm4.w+sm4.w;
      float part = mkx*q4.x + mky*q4.y + mkz*q4.z + mkw*q4.w;
      part = group16_sum(part);
      float l = valid ? part : -3.4e38f;
      float mn = fmaxf(m, l);
      float scale = __expf(m - mn);
      float wgt = valid ? __expf(l - mn) : 0.f;
      ax = ax*scale + wgt*mkx; ay = ay*scale + wgt*mky;
      az = az*scale + wgt*mkz; aw = aw*scale + wgt*mkw;
      dsum = dsum*scale + wgt;
      m = mn;
    }
    float mg = fmaxf(m, __shfl_xor(m, 16, 64));
    mg = fmaxf(mg, __shfl_xor(mg, 32, 64));
    float cs = __expf(m - mg);
    ax*=cs; ay*=cs; az*=cs; aw*=cs; dsum*=cs;
    ax = xgroup_sum(ax); ay = xgroup_sum(ay); az = xgroup_sum(az); aw = xgroup_sum(aw);
    dsum = xgroup_sum(dsum);
    if (lane < 16){
      float inv = 1.f/(dsum + EPSF);
      aggl[w*64 + dl+0] = ax*inv;
      aggl[w*64 + dl+1] = ay*inv;
      aggl[w*64 + dl+2] = az*inv;
      aggl[w*64 + dl+3] = aw*inv;
    }
    float o = 0.f;
    #pragma unroll 8
    for (int j=0;j<64;j++) o = fmaf(aggl[w*64 + j], Wl[j*64 + lane], o);
    he_next[(size_t)h*64 + lane] = tanhf(o);
  }
}

// ---------------- per-member-slot aggregation; persistent grid ----------------
__global__ __launch_bounds__(256) void k_nodeagg2(const int* __restrict__ mcountp,
    const int* __restrict__ off_slot, const unsigned* __restrict__ edge_src,
    const float* __restrict__ he_next, const float* __restrict__ sema,
    float* __restrict__ nagg, float* __restrict__ oagg){
  __shared__ float sm_lds[640];
  int t = threadIdx.x;
  for (int i=t;i<640;i+=256) sm_lds[i] = sema[i];
  __syncthreads();
  int w = t >> 6, lane = t & 63;
  int mc = *mcountp;
  int npb = (mc + 3) >> 2;
  int g = lane >> 4, dl = (lane & 15)*4;
  for (int pb = blockIdx.x; pb < npb; pb += gridDim.x){
    int p = pb*4 + w;
    if (p >= mc) continue;
    int start = off_slot[p], end = off_slot[p+1];
    float anx=0.f, any_=0.f, anz=0.f, anw=0.f;
    float aox=0.f, aoy=0.f, aoz=0.f, aow=0.f;
    for (int idx0 = start; idx0 < end; idx0 += 4){
      int idx = idx0 + g;
      if (idx < end){
        unsigned u = edge_src[idx];
        int hd = u & 0xFFFFF, sem = u >> 20;
        float4 hv = *(const float4*)&he_next[(size_t)hd*64 + dl];
        float4 sv = *(const float4*)&sm_lds[sem*64 + dl];
        anx += hv.x; any_ += hv.y; anz += hv.z; anw += hv.w;
        aox = fmaf(hv.x, sv.x, aox); aoy = fmaf(hv.y, sv.y, aoy);
        aoz = fmaf(hv.z, sv.z, aoz); aow = fmaf(hv.w, sv.w, aow);
      }
    }
    anx = xgroup_sum(anx); any_ = xgroup_sum(any_); anz = xgroup_sum(anz); anw = xgroup_sum(anw);
    aox = xgroup_sum(aox); aoy = xgroup_sum(aoy); aoz = xgroup_sum(aoz); aow = xgroup_sum(aow);
    if (lane < 16){
      float inv = 1.f/((float)(end - start) + EPSF);
      *(float4*)&nagg[(size_t)p*64 + dl] = make_float4(anx*inv, any_*inv, anz*inv, anw*inv);
      *(float4*)&oagg[(size_t)p*64 + dl] = make_float4(aox*inv, aoy*inv, aoz*inv, aow*inv);
    }
  }
}

// ---------------- fused mat2+mat3, sequential-W (one 16KB W buffer) ----------------
// inner = leaky(inner1 + nagg@Wi2); ne[mlist] = tanh(inner@Wn + oagg@We + nagg@Ws)
__global__ __launch_bounds__(256) void k_matfuse(const float* __restrict__ inner1, const float* __restrict__ nagg,
    const float* __restrict__ oagg, const float* __restrict__ Wi2, const float* __restrict__ Wn,
    const float* __restrict__ We, const float* __restrict__ Ws,
    const int* __restrict__ mlist, const int* __restrict__ mcountp, float* __restrict__ ne){
  __shared__ float Wl[4096];
  __shared__ float Ai[16][65], An[16][65], Ao[16][65];
  int t = threadIdx.x;
  int cnt = *mcountp;
  int ntiles = (cnt + 15) >> 4;
  int rr = t >> 4, cg = t & 15;
  int cg4 = cg*4;
  for (int tile = blockIdx.x; tile < ntiles; tile += gridDim.x){
    __syncthreads();
    int r = tile*16 + rr;
    if (r < cnt){
      float4 v = *(const float4*)&inner1[(size_t)r*64 + cg4];
      Ai[rr][cg4+0]=v.x; Ai[rr][cg4+1]=v.y; Ai[rr][cg4+2]=v.z; Ai[rr][cg4+3]=v.w;
      float4 u = *(const float4*)&nagg[(size_t)r*64 + cg4];
      An[rr][cg4+0]=u.x; An[rr][cg4+1]=u.y; An[rr][cg4+2]=u.z; An[rr][cg4+3]=u.w;
      float4 z = *(const float4*)&oagg[(size_t)r*64 + cg4];
      Ao[rr][cg4+0]=z.x; Ao[rr][cg4+1]=z.y; Ao[rr][cg4+2]=z.z; Ao[rr][cg4+3]=z.w;
    }
    LOAD_W(Wl, Wi2)
    __syncthreads();
    // phase 1: inner = leaky(inner1 + nagg@Wi2); each thread touches only its own Ai slots
    float4 p1 = gemv16(Wl, An, rr, cg4);
    float x0 = p1.x + Ai[rr][cg4+0], x1 = p1.y + Ai[rr][cg4+1];
    float x2 = p1.z + Ai[rr][cg4+2], x3 = p1.w + Ai[rr][cg4+3];
    Ai[rr][cg4+0] = x0 >= 0.f ? x0 : 0.01f*x0;
    Ai[rr][cg4+1] = x1 >= 0.f ? x1 : 0.01f*x1;
    Ai[rr][cg4+2] = x2 >= 0.f ? x2 : 0.01f*x2;
    Ai[rr][cg4+3] = x3 >= 0.f ? x3 : 0.01f*x3;
    __syncthreads();
    LOAD_W(Wl, Wn)
    __syncthreads();
    float4 acc = gemv16(Wl, Ai, rr, cg4);
    __syncthreads();
    LOAD_W(Wl, We)
    __syncthreads();
    float4 e = gemv16(Wl, Ao, rr, cg4);
    acc.x += e.x; acc.y += e.y; acc.z += e.z; acc.w += e.w;
    __syncthreads();
    LOAD_W(Wl, Ws)
    __syncthreads();
    float4 s = gemv16(Wl, An, rr, cg4);
    acc.x += s.x; acc.y += s.y; acc.z += s.z; acc.w += s.w;
    if (r < cnt){
      float4 o = make_float4(tanhf(acc.x), tanhf(acc.y), tanhf(acc.z), tanhf(acc.w));
      *(float4*)&ne[(size_t)mlist[r]*64 + cg4] = o;
    }
  }
}

extern "C" void kernel_launch(void* const* d_in, const int* in_sizes, int n_in,
                              void* d_out, int out_size, void* d_ws, size_t ws_size,
                              hipStream_t stream)
{
  (void)in_sizes; (void)n_in; (void)out_size; (void)ws_size;
  const float* node_emb  = (const float*)d_in[0];
  const float* hyper_emb = (const float*)d_in[1];
  const float* sema_emb  = (const float*)d_in[2];
  const float* W_msg = (const float*)d_in[3];
  const float* W_att = (const float*)d_in[4];
  const float* W_upd = (const float*)d_in[5];
  const float* Wi1   = (const float*)d_in[6];
  const float* Wi2   = (const float*)d_in[7];
  const float* Wo_n  = (const float*)d_in[8];
  const float* Wo_e  = (const float*)d_in[9];
  const float* Wo_s  = (const float*)d_in[10];
  const int* node_indices = (const int*)d_in[11];
  const int* semalinks    = (const int*)d_in[14];

  constexpr int N = 100000, H = 20000, NS = 10, L = 2, E = 1000000, NB = 50000;

  float* out_ne = (float*)d_out;                    // N*64
  float* out_he = (float*)d_out + (size_t)N*64;     // H*64

  char* wsp = (char*)d_ws;
  auto alloc = [&](size_t bytes)->char*{ char* p = wsp; wsp += (bytes + 255) & ~(size_t)255; return p; };
  char* zstart = wsp;
  int* member   = (int*)alloc((size_t)N*4);
  int* cnt_hed  = (int*)alloc((size_t)H*4);
  int* cnt_slot = (int*)alloc((size_t)NSLOT*4);
  int* cur_hed  = (int*)alloc((size_t)H*4);
  int* cur_slot = (int*)alloc((size_t)NSLOT*4);
  int* mcount   = (int*)alloc(256);
  size_t zbytes = (size_t)(wsp - zstart);
  int* off_hed   = (int*)alloc((size_t)(H+1)*4);
  int* off_slot  = (int*)alloc((size_t)(NSLOT+1)*4);
  int* mlist     = (int*)alloc((size_t)NB*4);
  int* partials  = (int*)alloc(256);
  ull* rec       = (ull*)alloc((size_t)E*8);
  unsigned* edge_hed = (unsigned*)alloc((size_t)E*4);
  unsigned* edge_src = (unsigned*)alloc((size_t)E*4);
  float* smbuf  = (float*)alloc((size_t)NS*64*4);
  float* hq     = (float*)alloc((size_t)H*64*4);
  float* nm_c   = (float*)alloc((size_t)NB*64*4);
  float* he1    = (float*)alloc((size_t)H*64*4);
  float* naggb  = (float*)alloc((size_t)NB*64*4);
  float* oaggb  = (float*)alloc((size_t)NB*64*4);
  float* inner1 = (float*)alloc((size_t)NB*64*4);

  hipMemsetAsync(zstart, 0, zbytes, stream);

  k_copy4<<<(N*64/4 + 255)/256, 256, 0, stream>>>((const float4*)node_emb, (float4*)out_ne, N*64/4);
  k_set_member<<<(NB+255)/256, 256, 0, stream>>>(node_indices, member, NB);
  k_build_list<<<(N+255)/256, 256, 0, stream>>>(member, mlist, mcount, N);
  k_rec<<<(E+255)/256, 256, 0, stream>>>(semalinks, member, rec, E);
  k_wcount<<<1024, 256, 0, stream>>>(rec, mcount, cnt_hed, cnt_slot, E);

  int nb_h = (H + 2047)/2048, nb_s = (NSLOT + 2047)/2048;
  k_scan1<<<nb_h, 256, 0, stream>>>(cnt_hed, off_hed, H, partials);
  k_scan2<<<1, 64, 0, stream>>>(partials, nb_h, off_hed, H);
  k_scan3<<<(H+255)/256, 256, 0, stream>>>(off_hed, partials, H);
  k_scan1<<<nb_s, 256, 0, stream>>>(cnt_slot, off_slot, NSLOT, partials);
  k_scan2<<<1, 64, 0, stream>>>(partials, nb_s, off_slot, NSLOT);
  k_scan3<<<(NSLOT+255)/256, 256, 0, stream>>>(off_slot, partials, NSLOT);

  k_scatter2<0><<<1024, 256, 0, stream>>>(rec, mcount, off_hed,  cur_hed,  edge_hed, E);
  k_scatter2<1><<<1024, 256, 0, stream>>>(rec, mcount, off_slot, cur_slot, edge_src, E);

  for (int i = 0; i < L; ++i){
    const float* Wm = W_msg + (size_t)i*4096;
    const float* Wa = W_att + (size_t)i*4096;
    const float* Wu = W_upd + (size_t)i*4096;
    const float* wi1 = Wi1 + (size_t)i*4096;
    const float* wi2 = Wi2 + (size_t)i*4096;
    const float* won = Wo_n + (size_t)i*4096;
    const float* woe = Wo_e + (size_t)i*4096;
    const float* wos = Wo_s + (size_t)i*4096;
    const float* he_cur = (i == 0) ? hyper_emb : he1;
    float* he_next = (i == 0) ? he1 : out_he;

    k_rowmatA<<<1280, 256, 0, stream>>>(out_ne, Wm, wi1, mlist, mcount, nm_c, inner1);
    k_rowmatB<<<1250, 256, 0, stream>>>(he_cur, sema_emb, Wa, Wm, hq, smbuf, H, NS);
    k_attn_upd<<<1280, 256, 0, stream>>>(off_hed, edge_hed, nm_c, smbuf, hq, Wu, he_cur, he_next, H);
    k_nodeagg2<<<1280, 256, 0, stream>>>(mcount, off_slot, edge_src, he_next, sema_emb, naggb, oaggb);
    k_matfuse<<<1280, 256, 0, stream>>>(inner1, naggb, oaggb, wi2, won, woe, wos, mlist, mcount, out_ne);
  }
}

// Round 11
// 383.924 us; speedup vs baseline: 1.2668x; 1.0949x over previous
//
#include <hip/hip_runtime.h>
#include <cmath>

// HyperKGL: N=100000, H=20000, NS=10, D=64, L=2, E=1e6, NB=50000
// R10 -> R11: 16-row GEMVs were LDS-instruction bound (2 LDS instr per 4 FMA;
// VALUBusy 23%). Rebuilt 4x4-register-blocked GEMM64 with At pad=68 (R9's pad 65
// made float4 At reads misaligned -> split b32). matfuse: ONE At buffer reused
// (An -> Ai(reg) -> Ao) + one W = 33.4KB LDS, 4 blocks/CU, 2 LDS : 16 FMA.

#define EPSF 1e-9f
#define NSLOT 40960
#define SENT 0xFFFFFFFFu
#define ATP 68
typedef unsigned long long ull;

__device__ __forceinline__ float group16_sum(float v){
  v += __shfl_xor(v, 1, 64);
  v += __shfl_xor(v, 2, 64);
  v += __shfl_xor(v, 4, 64);
  v += __shfl_xor(v, 8, 64);
  return v;
}
__device__ __forceinline__ float xgroup_sum(float v){
  v += __shfl_xor(v, 16, 64);
  v += __shfl_xor(v, 32, 64);
  return v;
}

// ---------------- setup ----------------
__global__ __launch_bounds__(256) void k_copy4(const float4* __restrict__ in, float4* __restrict__ out, int n){
  int i = blockIdx.x*256 + threadIdx.x;
  if (i < n) out[i] = in[i];
}

__global__ __launch_bounds__(256) void k_set_member(const int* __restrict__ idx, int* __restrict__ member, int n){
  int i = blockIdx.x*256 + threadIdx.x;
  if (i < n) member[idx[i]] = 1;
}

__global__ __launch_bounds__(256) void k_build_list(int* __restrict__ member, int* __restrict__ mlist,
                                                    int* __restrict__ mcount, int N){
  int n = blockIdx.x*256 + threadIdx.x;
  if (n < N && member[n]) {
    int p = atomicAdd(mcount, 1);
    mlist[p] = n;
    member[n] = p + 2;   // slot+2 (0 = non-member)
  }
}

__global__ __launch_bounds__(256) void k_rec(const int* __restrict__ sl, const int* __restrict__ member,
                                             ull* __restrict__ rec, int E){
  int e = blockIdx.x*256 + threadIdx.x;
  if (e >= E) return;
  int src = sl[3*e];
  int m = member[src];
  if (m){
    unsigned lo = (unsigned)(m-2) | ((unsigned)sl[3*e+2] << 20);
    rec[e] = (ull)lo | ((ull)(unsigned)sl[3*e+1] << 32);
  } else {
    rec[e] = (ull)SENT << 32;
  }
}

__global__ __launch_bounds__(256) void k_wcount(const ull* __restrict__ rec, const int* __restrict__ mcountp,
    int* __restrict__ cnt_hed, int* __restrict__ cnt_slot, int E){
  int w = blockIdx.x & 7;
  int chunk = blockIdx.x >> 3;
  int nchunk = gridDim.x >> 3;
  int per = (E + nchunk - 1) / nchunk;
  int lo_i = chunk * per;
  int hi_i = min(E, lo_i + per);
  int divs = (*mcountp + 7) >> 3;
  for (int i = lo_i + threadIdx.x; i < hi_i; i += 256){
    ull r = rec[i];
    unsigned hed = (unsigned)(r >> 32);
    if (hed == SENT) continue;
    int slot = (int)(r & 0xFFFFF);
    if ((int)hed / 2500 == w) atomicAdd(&cnt_hed[hed], 1);
    if (slot / divs   == w) atomicAdd(&cnt_slot[slot], 1);
  }
}

__global__ __launch_bounds__(256) void k_scan1(const int* __restrict__ in, int* __restrict__ out, int n,
                                               int* __restrict__ partials){
  __shared__ int s[256];
  int b = blockIdx.x, t = threadIdx.x;
  int base = b*2048 + t*8;
  int v[8]; int sum = 0;
  #pragma unroll
  for (int j=0;j<8;j++){ int i = base + j; v[j] = (i<n) ? in[i] : 0; sum += v[j]; }
  s[t] = sum;
  __syncthreads();
  for (int o=1;o<256;o<<=1){
    int x = (t>=o) ? s[t-o] : 0;
    __syncthreads();
    s[t] += x;
    __syncthreads();
  }
  int excl = s[t] - sum;
  if (t == 255) partials[b] = s[255];
  int run = excl;
  #pragma unroll
  for (int j=0;j<8;j++){ int i = base + j; if (i<n) out[i] = run; run += v[j]; }
}

__global__ void k_scan2(int* __restrict__ partials, int nb, int* __restrict__ out, int n){
  if (threadIdx.x==0 && blockIdx.x==0){
    int run = 0;
    for (int i=0;i<nb;i++){ int x = partials[i]; partials[i] = run; run += x; }
    out[n] = run;
  }
}

__global__ __launch_bounds__(256) void k_scan3(int* __restrict__ out, const int* __restrict__ partials, int n){
  int i = blockIdx.x*256 + threadIdx.x;
  if (i < n) out[i] += partials[i >> 11];
}

template<int KEY>
__global__ __launch_bounds__(256) void k_scatter2(const ull* __restrict__ rec,
    const int* __restrict__ mcountp,
    const int* __restrict__ off, int* __restrict__ cur, unsigned* __restrict__ dst, int E){
  int w = blockIdx.x & 7;
  int chunk = blockIdx.x >> 3;
  int nchunk = gridDim.x >> 3;
  int per = (E + nchunk - 1) / nchunk;
  int lo_i = chunk * per;
  int hi_i = min(E, lo_i + per);
  int div = KEY ? ((*mcountp + 7) >> 3) : 2500;
  for (int i = lo_i + threadIdx.x; i < hi_i; i += 256){
    ull r = rec[i];
    unsigned hed = (unsigned)(r >> 32);
    if (hed == SENT) continue;
    unsigned lo = (unsigned)r;
    int slot = lo & 0xFFFFF;
    int key = KEY ? slot : (int)hed;
    if (key / div != w) continue;
    unsigned payload = KEY ? (hed | (lo & 0xFFF00000u)) : lo;
    int p = off[key] + atomicAdd(&cur[key], 1);
    dst[p] = payload;
  }
}

// ================= 4x4 register-blocked GEMM64 =================
// 256 threads: cg = t&15 (cols cg*4..+3), rg = t>>4 (rows rg*4..+3).
// At transposed [64][ATP=68]: aligned float4 reads At[k][rg4], 4-addr broadcast.

#define LOAD_W(Wl, Wsrc) for (int i_=threadIdx.x; i_<1024; i_+=256) ((float4*)Wl)[i_] = ((const float4*)(Wsrc))[i_];

// stage 64 rows (ro.., guard nrows) transposed into At
#define STAGE_AT(At, ro, nrows, LOADEXPR)                              \
  {                                                                    \
    int cg_ = threadIdx.x & 15, rl_ = threadIdx.x >> 4;                \
    for (int p_ = 0; p_ < 4; ++p_){                                    \
      int rloc_ = p_*16 + rl_;                                         \
      int r_ = (ro) + rloc_;                                           \
      float4 v_ = make_float4(0.f,0.f,0.f,0.f);                        \
      if (r_ < (nrows)){ v_ = (LOADEXPR); }                            \
      At[cg_*4+0][rloc_] = v_.x;                                       \
      At[cg_*4+1][rloc_] = v_.y;                                       \
      At[cg_*4+2][rloc_] = v_.z;                                       \
      At[cg_*4+3][rloc_] = v_.w;                                       \
    }                                                                  \
  }

__device__ __forceinline__ void gemm44(const float* __restrict__ Wl, const float (*At)[ATP],
                                       int rg4, int cg4, float4 acc[4]){
  #pragma unroll 8
  for (int k = 0; k < 64; ++k){
    const float4 w = *(const float4*)&Wl[k*64 + cg4];
    const float4 a = *(const float4*)&At[k][rg4];
    acc[0].x = fmaf(a.x,w.x,acc[0].x); acc[0].y = fmaf(a.x,w.y,acc[0].y);
    acc[0].z = fmaf(a.x,w.z,acc[0].z); acc[0].w = fmaf(a.x,w.w,acc[0].w);
    acc[1].x = fmaf(a.y,w.x,acc[1].x); acc[1].y = fmaf(a.y,w.y,acc[1].y);
    acc[1].z = fmaf(a.y,w.z,acc[1].z); acc[1].w = fmaf(a.y,w.w,acc[1].w);
    acc[2].x = fmaf(a.z,w.x,acc[2].x); acc[2].y = fmaf(a.z,w.y,acc[2].y);
    acc[2].z = fmaf(a.z,w.z,acc[2].z); acc[2].w = fmaf(a.z,w.w,acc[2].w);
    acc[3].x = fmaf(a.w,w.x,acc[3].x); acc[3].y = fmaf(a.w,w.y,acc[3].y);
    acc[3].z = fmaf(a.w,w.z,acc[3].z); acc[3].w = fmaf(a.w,w.w,acc[3].w);
  }
}

#define ZERO4(a) { a[0]=make_float4(0,0,0,0); a[1]=make_float4(0,0,0,0); a[2]=make_float4(0,0,0,0); a[3]=make_float4(0,0,0,0); }

// rowmatA: nm = ne[mlist]@Wm ; inner1 = ne[mlist]@Wi1 (both W resident, 49KB)
__global__ __launch_bounds__(256) void k_rowmatA(const float* __restrict__ ne, const float* __restrict__ Wm,
    const float* __restrict__ Wi1, const int* __restrict__ mlist, const int* __restrict__ mcountp,
    float* __restrict__ nm, float* __restrict__ inner1){
  __shared__ float W1[4096], W2[4096];
  __shared__ float At[64][ATP];
  int t = threadIdx.x;
  int nrows = *mcountp;
  int ntiles = (nrows + 63) >> 6;
  LOAD_W(W1, Wm)
  LOAD_W(W2, Wi1)
  int cg4 = (t & 15)*4, rg4 = (t >> 4)*4;
  for (int tile = blockIdx.x; tile < ntiles; tile += gridDim.x){
    int ro = tile << 6;
    __syncthreads();
    STAGE_AT(At, ro, nrows, (*(const float4*)&ne[(size_t)mlist[r_]*64 + cg_*4]))
    __syncthreads();
    float4 a1[4]; ZERO4(a1)
    float4 a2[4]; ZERO4(a2)
    #pragma unroll 4
    for (int k = 0; k < 64; ++k){
      const float4 w1 = *(const float4*)&W1[k*64 + cg4];
      const float4 w2 = *(const float4*)&W2[k*64 + cg4];
      const float4 a  = *(const float4*)&At[k][rg4];
      a1[0].x=fmaf(a.x,w1.x,a1[0].x); a1[0].y=fmaf(a.x,w1.y,a1[0].y); a1[0].z=fmaf(a.x,w1.z,a1[0].z); a1[0].w=fmaf(a.x,w1.w,a1[0].w);
      a1[1].x=fmaf(a.y,w1.x,a1[1].x); a1[1].y=fmaf(a.y,w1.y,a1[1].y); a1[1].z=fmaf(a.y,w1.z,a1[1].z); a1[1].w=fmaf(a.y,w1.w,a1[1].w);
      a1[2].x=fmaf(a.z,w1.x,a1[2].x); a1[2].y=fmaf(a.z,w1.y,a1[2].y); a1[2].z=fmaf(a.z,w1.z,a1[2].z); a1[2].w=fmaf(a.z,w1.w,a1[2].w);
      a1[3].x=fmaf(a.w,w1.x,a1[3].x); a1[3].y=fmaf(a.w,w1.y,a1[3].y); a1[3].z=fmaf(a.w,w1.z,a1[3].z); a1[3].w=fmaf(a.w,w1.w,a1[3].w);
      a2[0].x=fmaf(a.x,w2.x,a2[0].x); a2[0].y=fmaf(a.x,w2.y,a2[0].y); a2[0].z=fmaf(a.x,w2.z,a2[0].z); a2[0].w=fmaf(a.x,w2.w,a2[0].w);
      a2[1].x=fmaf(a.y,w2.x,a2[1].x); a2[1].y=fmaf(a.y,w2.y,a2[1].y); a2[1].z=fmaf(a.y,w2.z,a2[1].z); a2[1].w=fmaf(a.y,w2.w,a2[1].w);
      a2[2].x=fmaf(a.z,w2.x,a2[2].x); a2[2].y=fmaf(a.z,w2.y,a2[2].y); a2[2].z=fmaf(a.z,w2.z,a2[2].z); a2[2].w=fmaf(a.z,w2.w,a2[2].w);
      a2[3].x=fmaf(a.w,w2.x,a2[3].x); a2[3].y=fmaf(a.w,w2.y,a2[3].y); a2[3].z=fmaf(a.w,w2.z,a2[3].z); a2[3].w=fmaf(a.w,w2.w,a2[3].w);
    }
    #pragma unroll
    for (int i = 0; i < 4; ++i){
      int r = ro + rg4 + i;
      if (r < nrows){
        *(float4*)&nm[(size_t)r*64 + cg4]     = a1[i];
        *(float4*)&inner1[(size_t)r*64 + cg4] = a2[i];
      }
    }
  }
}

// rowmatB: hq = he@Wa ; block 0 prologue: smbuf = sema@Wm
__global__ __launch_bounds__(256) void k_rowmatB(const float* __restrict__ he, const float* __restrict__ sema,
    const float* __restrict__ Wa, const float* __restrict__ Wm,
    float* __restrict__ hq, float* __restrict__ smbuf, int H, int NS_){
  __shared__ float W1[4096];
  __shared__ float At[64][ATP];
  int t = threadIdx.x;
  if (blockIdx.x == 0 && t < 160){
    int sr = t >> 4, c4 = (t & 15)*4;
    float4 accs = make_float4(0,0,0,0);
    #pragma unroll 8
    for (int k = 0; k < 64; ++k){
      float a = sema[sr*64 + k];
      float4 w = *(const float4*)&Wm[k*64 + c4];
      accs.x = fmaf(a,w.x,accs.x); accs.y = fmaf(a,w.y,accs.y);
      accs.z = fmaf(a,w.z,accs.z); accs.w = fmaf(a,w.w,accs.w);
    }
    *(float4*)&smbuf[(size_t)sr*64 + c4] = accs;
  }
  LOAD_W(W1, Wa)
  int nrows = H;
  int ntiles = (nrows + 63) >> 6;
  int cg4 = (t & 15)*4, rg4 = (t >> 4)*4;
  for (int tile = blockIdx.x; tile < ntiles; tile += gridDim.x){
    int ro = tile << 6;
    __syncthreads();
    STAGE_AT(At, ro, nrows, (*(const float4*)&he[(size_t)r_*64 + cg_*4]))
    __syncthreads();
    float4 acc[4]; ZERO4(acc)
    gemm44(W1, At, rg4, cg4, acc);
    #pragma unroll
    for (int i = 0; i < 4; ++i){
      int r = ro + rg4 + i;
      if (r < nrows) *(float4*)&hq[(size_t)r*64 + cg4] = acc[i];
    }
  }
}

// matfuse: inner = leaky(inner1 + nagg@Wi2); ne[mlist] = tanh(inner@Wn + oagg@We + nagg@Ws)
// ONE At buffer: An -> Ai (reg-written transposed) -> Ao. One W buffer. 33.4KB LDS.
__global__ __launch_bounds__(256) void k_matfuse(const float* __restrict__ inner1, const float* __restrict__ nagg,
    const float* __restrict__ oagg, const float* __restrict__ Wi2, const float* __restrict__ Wn,
    const float* __restrict__ We, const float* __restrict__ Ws,
    const int* __restrict__ mlist, const int* __restrict__ mcountp, float* __restrict__ ne){
  __shared__ float Wl[4096];
  __shared__ float At[64][ATP];
  int t = threadIdx.x;
  int cnt = *mcountp;
  int ntiles = (cnt + 63) >> 6;
  int cg4 = (t & 15)*4, rg4 = (t >> 4)*4;
  for (int tile = blockIdx.x; tile < ntiles; tile += gridDim.x){
    int ro = tile << 6;
    __syncthreads();                 // protect At/W reuse from previous iteration
    STAGE_AT(At, ro, cnt, (*(const float4*)&nagg[(size_t)r_*64 + cg_*4]))
    LOAD_W(Wl, Ws)
    __syncthreads();
    float4 acc[4]; ZERO4(acc)
    gemm44(Wl, At, rg4, cg4, acc);   // acc = An@Ws
    __syncthreads();
    LOAD_W(Wl, Wi2)
    __syncthreads();
    float4 p1[4]; ZERO4(p1)
    gemm44(Wl, At, rg4, cg4, p1);    // p1 = An@Wi2
    // x = leaky(p1 + inner1) per-thread (rows rg4..+3, cols cg4..+3)
    float x[4][4];
    #pragma unroll
    for (int i = 0; i < 4; ++i){
      int r = ro + rg4 + i;
      float4 v = make_float4(0.f,0.f,0.f,0.f);
      if (r < cnt) v = *(const float4*)&inner1[(size_t)r*64 + cg4];
      float x0 = p1[i].x + v.x, x1 = p1[i].y + v.y, x2 = p1[i].z + v.z, x3 = p1[i].w + v.w;
      x[i][0] = x0 >= 0.f ? x0 : 0.01f*x0;
      x[i][1] = x1 >= 0.f ? x1 : 0.01f*x1;
      x[i][2] = x2 >= 0.f ? x2 : 0.01f*x2;
      x[i][3] = x3 >= 0.f ? x3 : 0.01f*x3;
    }
    __syncthreads();                 // everyone done reading An
    #pragma unroll
    for (int i = 0; i < 4; ++i)
      #pragma unroll
      for (int j = 0; j < 4; ++j)
        At[cg4+j][rg4+i] = x[i][j];  // Ai transposed (one-time 8-way conflict)
    LOAD_W(Wl, Wn)
    __syncthreads();
    gemm44(Wl, At, rg4, cg4, acc);   // acc += Ai@Wn
    __syncthreads();                 // done reading Ai
    STAGE_AT(At, ro, cnt, (*(const float4*)&oagg[(size_t)r_*64 + cg_*4]))
    LOAD_W(Wl, We)
    __syncthreads();
    gemm44(Wl, At, rg4, cg4, acc);   // acc += Ao@We
    #pragma unroll
    for (int i = 0; i < 4; ++i){
      int r = ro + rg4 + i;
      if (r < cnt){
        float4 o = make_float4(tanhf(acc[i].x), tanhf(acc[i].y), tanhf(acc[i].z), tanhf(acc[i].w));
        *(float4*)&ne[(size_t)mlist[r]*64 + cg4] = o;
      }
    }
  }
}

// ---------------- attention + W_upd matvec fused; persistent grid ----------------
__global__ __launch_bounds__(256) void k_attn_upd(const int* __restrict__ off_hed, const unsigned* __restrict__ edge_hed,
    const float* __restrict__ nm_c, const float* __restrict__ smb, const float* __restrict__ hq,
    const float* __restrict__ W, const float* __restrict__ he_cur, float* __restrict__ he_next, int H){
  __shared__ float Wl[4096];
  __shared__ float sm_lds[640];
  __shared__ float aggl[256];
  int t = threadIdx.x;
  for (int i=t;i<1024;i+=256) ((float4*)Wl)[i] = ((const float4*)W)[i];
  for (int i=t;i<640;i+=256) sm_lds[i] = smb[i];
  __syncthreads();
  int w = t >> 6, lane = t & 63;
  int nhb = (H + 3) >> 2;
  for (int hb = blockIdx.x; hb < nhb; hb += gridDim.x){
    int h = hb*4 + w;
    if (h >= H) continue;
    int start = off_hed[h], end = off_hed[h+1];
    if (start == end){
      he_next[(size_t)h*64 + lane] = he_cur[(size_t)h*64 + lane];
      continue;
    }
    int g = lane >> 4, dl = (lane & 15)*4;
    float4 q4 = *(const float4*)&hq[(size_t)h*64 + dl];
    float ax=0.f, ay=0.f, az=0.f, aw=0.f, dsum=0.f, m=-3.4e38f;
    for (int idx0 = start; idx0 < end; idx0 += 4){
      int idx = idx0 + g;
      bool valid = idx < end;
      unsigned u = valid ? edge_hed[idx] : 0u;
      int slot = u & 0xFFFFF, sem = u >> 20;
      float4 nm4 = make_float4(0.f,0.f,0.f,0.f);
      if (valid) nm4 = *(const float4*)&nm_c[(size_t)slot*64 + dl];
      float4 sm4 = *(const float4*)&sm_lds[sem*64 + dl];
      float mkx = nm4.x+sm4.x, mky = nm4.y+sm4.y, mkz = nm4.z+sm4.z, mkw = nm4.w+sm4.w;
      float part = mkx*q4.x + mky*q4.y + mkz*q4.z + mkw*q4.w;
      part = group16_sum(part);
      float l = valid ? part : -3.4e38f;
      float mn = fmaxf(m, l);
      float scale = __expf(m - mn);
      float wgt = valid ? __expf(l - mn) : 0.f;
      ax = ax*scale + wgt*mkx; ay = ay*scale + wgt*mky;
      az = az*scale + wgt*mkz; aw = aw*scale + wgt*mkw;
      dsum = dsum*scale + wgt;
      m = mn;
    }
    float mg = fmaxf(m, __shfl_xor(m, 16, 64));
    mg = fmaxf(mg, __shfl_xor(mg, 32, 64));
    float cs = __expf(m - mg);
    ax*=cs; ay*=cs; az*=cs; aw*=cs; dsum*=cs;
    ax = xgroup_sum(ax); ay = xgroup_sum(ay); az = xgroup_sum(az); aw = xgroup_sum(aw);
    dsum = xgroup_sum(dsum);
    if (lane < 16){
      float inv = 1.f/(dsum + EPSF);
      aggl[w*64 + dl+0] = ax*inv;
      aggl[w*64 + dl+1] = ay*inv;
      aggl[w*64 + dl+2] = az*inv;
      aggl[w*64 + dl+3] = aw*inv;
    }
    float o = 0.f;
    #pragma unroll 8
    for (int j=0;j<64;j++) o = fmaf(aggl[w*64 + j], Wl[j*64 + lane], o);
    he_next[(size_t)h*64 + lane] = tanhf(o);
  }
}

// ---------------- per-member-slot aggregation; persistent grid ----------------
__global__ __launch_bounds__(256) void k_nodeagg2(const int* __restrict__ mcountp,
    const int* __restrict__ off_slot, const unsigned* __restrict__ edge_src,
    const float* __restrict__ he_next, const float* __restrict__ sema,
    float* __restrict__ nagg, float* __restrict__ oagg){
  __shared__ float sm_lds[640];
  int t = threadIdx.x;
  for (int i=t;i<640;i+=256) sm_lds[i] = sema[i];
  __syncthreads();
  int w = t >> 6, lane = t & 63;
  int mc = *mcountp;
  int npb = (mc + 3) >> 2;
  int g = lane >> 4, dl = (lane & 15)*4;
  for (int pb = blockIdx.x; pb < npb; pb += gridDim.x){
    int p = pb*4 + w;
    if (p >= mc) continue;
    int start = off_slot[p], end = off_slot[p+1];
    float anx=0.f, any_=0.f, anz=0.f, anw=0.f;
    float aox=0.f, aoy=0.f, aoz=0.f, aow=0.f;
    for (int idx0 = start; idx0 < end; idx0 += 4){
      int idx = idx0 + g;
      if (idx < end){
        unsigned u = edge_src[idx];
        int hd = u & 0xFFFFF, sem = u >> 20;
        float4 hv = *(const float4*)&he_next[(size_t)hd*64 + dl];
        float4 sv = *(const float4*)&sm_lds[sem*64 + dl];
        anx += hv.x; any_ += hv.y; anz += hv.z; anw += hv.w;
        aox = fmaf(hv.x, sv.x, aox); aoy = fmaf(hv.y, sv.y, aoy);
        aoz = fmaf(hv.z, sv.z, aoz); aow = fmaf(hv.w, sv.w, aow);
      }
    }
    anx = xgroup_sum(anx); any_ = xgroup_sum(any_); anz = xgroup_sum(anz); anw = xgroup_sum(anw);
    aox = xgroup_sum(aox); aoy = xgroup_sum(aoy); aoz = xgroup_sum(aoz); aow = xgroup_sum(aow);
    if (lane < 16){
      float inv = 1.f/((float)(end - start) + EPSF);
      *(float4*)&nagg[(size_t)p*64 + dl] = make_float4(anx*inv, any_*inv, anz*inv, anw*inv);
      *(float4*)&oagg[(size_t)p*64 + dl] = make_float4(aox*inv, aoy*inv, aoz*inv, aow*inv);
    }
  }
}

extern "C" void kernel_launch(void* const* d_in, const int* in_sizes, int n_in,
                              void* d_out, int out_size, void* d_ws, size_t ws_size,
                              hipStream_t stream)
{
  (void)in_sizes; (void)n_in; (void)out_size; (void)ws_size;
  const float* node_emb  = (const float*)d_in[0];
  const float* hyper_emb = (const float*)d_in[1];
  const float* sema_emb  = (const float*)d_in[2];
  const float* W_msg = (const float*)d_in[3];
  const float* W_att = (const float*)d_in[4];
  const float* W_upd = (const float*)d_in[5];
  const float* Wi1   = (const float*)d_in[6];
  const float* Wi2   = (const float*)d_in[7];
  const float* Wo_n  = (const float*)d_in[8];
  const float* Wo_e  = (const float*)d_in[9];
  const float* Wo_s  = (const float*)d_in[10];
  const int* node_indices = (const int*)d_in[11];
  const int* semalinks    = (const int*)d_in[14];

  constexpr int N = 100000, H = 20000, NS = 10, L = 2, E = 1000000, NB = 50000;

  float* out_ne = (float*)d_out;                    // N*64
  float* out_he = (float*)d_out + (size_t)N*64;     // H*64

  char* wsp = (char*)d_ws;
  auto alloc = [&](size_t bytes)->char*{ char* p = wsp; wsp += (bytes + 255) & ~(size_t)255; return p; };
  char* zstart = wsp;
  int* member   = (int*)alloc((size_t)N*4);
  int* cnt_hed  = (int*)alloc((size_t)H*4);
  int* cnt_slot = (int*)alloc((size_t)NSLOT*4);
  int* cur_hed  = (int*)alloc((size_t)H*4);
  int* cur_slot = (int*)alloc((size_t)NSLOT*4);
  int* mcount   = (int*)alloc(256);
  size_t zbytes = (size_t)(wsp - zstart);
  int* off_hed   = (int*)alloc((size_t)(H+1)*4);
  int* off_slot  = (int*)alloc((size_t)(NSLOT+1)*4);
  int* mlist     = (int*)alloc((size_t)NB*4);
  int* partials  = (int*)alloc(256);
  ull* rec       = (ull*)alloc((size_t)E*8);
  unsigned* edge_hed = (unsigned*)alloc((size_t)E*4);
  unsigned* edge_src = (unsigned*)alloc((size_t)E*4);
  float* smbuf  = (float*)alloc((size_t)NS*64*4);
  float* hq     = (float*)alloc((size_t)H*64*4);
  float* nm_c   = (float*)alloc((size_t)NB*64*4);
  float* he1    = (float*)alloc((size_t)H*64*4);
  float* naggb  = (float*)alloc((size_t)NB*64*4);
  float* oaggb  = (float*)alloc((size_t)NB*64*4);
  float* inner1 = (float*)alloc((size_t)NB*64*4);

  hipMemsetAsync(zstart, 0, zbytes, stream);

  k_copy4<<<(N*64/4 + 255)/256, 256, 0, stream>>>((const float4*)node_emb, (float4*)out_ne, N*64/4);
  k_set_member<<<(NB+255)/256, 256, 0, stream>>>(node_indices, member, NB);
  k_build_list<<<(N+255)/256, 256, 0, stream>>>(member, mlist, mcount, N);
  k_rec<<<(E+255)/256, 256, 0, stream>>>(semalinks, member, rec, E);
  k_wcount<<<1024, 256, 0, stream>>>(rec, mcount, cnt_hed, cnt_slot, E);

  int nb_h = (H + 2047)/2048, nb_s = (NSLOT + 2047)/2048;
  k_scan1<<<nb_h, 256, 0, stream>>>(cnt_hed, off_hed, H, partials);
  k_scan2<<<1, 64, 0, stream>>>(partials, nb_h, off_hed, H);
  k_scan3<<<(H+255)/256, 256, 0, stream>>>(off_hed, partials, H);
  k_scan1<<<nb_s, 256, 0, stream>>>(cnt_slot, off_slot, NSLOT, partials);
  k_scan2<<<1, 64, 0, stream>>>(partials, nb_s, off_slot, NSLOT);
  k_scan3<<<(NSLOT+255)/256, 256, 0, stream>>>(off_slot, partials, NSLOT);

  k_scatter2<0><<<1024, 256, 0, stream>>>(rec, mcount, off_hed,  cur_hed,  edge_hed, E);
  k_scatter2<1><<<1024, 256, 0, stream>>>(rec, mcount, off_slot, cur_slot, edge_src, E);

  for (int i = 0; i < L; ++i){
    const float* Wm = W_msg + (size_t)i*4096;
    const float* Wa = W_att + (size_t)i*4096;
    const float* Wu = W_upd + (size_t)i*4096;
    const float* wi1 = Wi1 + (size_t)i*4096;
    const float* wi2 = Wi2 + (size_t)i*4096;
    const float* won = Wo_n + (size_t)i*4096;
    const float* woe = Wo_e + (size_t)i*4096;
    const float* wos = Wo_s + (size_t)i*4096;
    const float* he_cur = (i == 0) ? hyper_emb : he1;
    float* he_next = (i == 0) ? he1 : out_he;

    k_rowmatA<<<800, 256, 0, stream>>>(out_ne, Wm, wi1, mlist, mcount, nm_c, inner1);
    k_rowmatB<<<320, 256, 0, stream>>>(he_cur, sema_emb, Wa, Wm, hq, smbuf, H, NS);
    k_attn_upd<<<1280, 256, 0, stream>>>(off_hed, edge_hed, nm_c, smbuf, hq, Wu, he_cur, he_next, H);
    k_nodeagg2<<<1280, 256, 0, stream>>>(mcount, off_slot, edge_src, he_next, sema_emb, naggb, oaggb);
    k_matfuse<<<800, 256, 0, stream>>>(inner1, naggb, oaggb, wi2, won, woe, wos, mlist, mcount, out_ne);
  }
}

// Round 12
// 363.029 us; speedup vs baseline: 1.3398x; 1.0576x over previous
//
#include <hip/hip_runtime.h>
#include <cmath>

// HyperKGL: N=100000, H=20000, NS=10, D=64, L=2, E=1e6, NB=50000
// R11 -> R12: (1) count fused back into record build (R5-style k_count_rec).
// (2) both XCD-windowed scatters merged into ONE scan of rec. (3) the two big
// per-edge gather tables (nm, he) stored as bf16 (RNE): halves the 2x200MB/layer
// gather streams; all accumulation stays f32.

#define EPSF 1e-9f
#define NSLOT 40960
#define SENT 0xFFFFFFFFu
#define ATP 68
typedef unsigned long long ull;

__device__ __forceinline__ float group16_sum(float v){
  v += __shfl_xor(v, 1, 64);
  v += __shfl_xor(v, 2, 64);
  v += __shfl_xor(v, 4, 64);
  v += __shfl_xor(v, 8, 64);
  return v;
}
__device__ __forceinline__ float xgroup_sum(float v){
  v += __shfl_xor(v, 16, 64);
  v += __shfl_xor(v, 32, 64);
  return v;
}
__device__ __forceinline__ unsigned short f2bf(float f){
  unsigned b = __float_as_uint(f);
  unsigned r = (b + 0x7FFFu + ((b >> 16) & 1u)) >> 16;
  return (unsigned short)r;
}
__device__ __forceinline__ float bf2f(unsigned short u){
  return __uint_as_float(((unsigned)u) << 16);
}

// ---------------- setup ----------------
__global__ __launch_bounds__(256) void k_copy4(const float4* __restrict__ in, float4* __restrict__ out, int n){
  int i = blockIdx.x*256 + threadIdx.x;
  if (i < n) out[i] = in[i];
}

__global__ __launch_bounds__(256) void k_set_member(const int* __restrict__ idx, int* __restrict__ member, int n){
  int i = blockIdx.x*256 + threadIdx.x;
  if (i < n) member[idx[i]] = 1;
}

__global__ __launch_bounds__(256) void k_build_list(int* __restrict__ member, int* __restrict__ mlist,
                                                    int* __restrict__ mcount, int N){
  int n = blockIdx.x*256 + threadIdx.x;
  if (n < N && member[n]) {
    int p = atomicAdd(mcount, 1);
    mlist[p] = n;
    member[n] = p + 2;   // slot+2 (0 = non-member)
  }
}

// record build + per-key degree counts in one streaming pass (R5-proven ~40us)
__global__ __launch_bounds__(256) void k_count_rec(const int* __restrict__ sl, const int* __restrict__ member,
    ull* __restrict__ rec, int* __restrict__ cnt_hed, int* __restrict__ cnt_slot, int E){
  int e = blockIdx.x*256 + threadIdx.x;
  if (e >= E) return;
  int src = sl[3*e];
  int m = member[src];
  if (m){
    int slot = m - 2;
    int hed = sl[3*e+1];
    int sem = sl[3*e+2];
    unsigned lo = (unsigned)slot | ((unsigned)sem << 20);
    rec[e] = (ull)lo | ((ull)(unsigned)hed << 32);
    atomicAdd(&cnt_hed[hed], 1);
    atomicAdd(&cnt_slot[slot], 1);
  } else {
    rec[e] = (ull)SENT << 32;
  }
}

__global__ __launch_bounds__(256) void k_scan1(const int* __restrict__ in, int* __restrict__ out, int n,
                                               int* __restrict__ partials){
  __shared__ int s[256];
  int b = blockIdx.x, t = threadIdx.x;
  int base = b*2048 + t*8;
  int v[8]; int sum = 0;
  #pragma unroll
  for (int j=0;j<8;j++){ int i = base + j; v[j] = (i<n) ? in[i] : 0; sum += v[j]; }
  s[t] = sum;
  __syncthreads();
  for (int o=1;o<256;o<<=1){
    int x = (t>=o) ? s[t-o] : 0;
    __syncthreads();
    s[t] += x;
    __syncthreads();
  }
  int excl = s[t] - sum;
  if (t == 255) partials[b] = s[255];
  int run = excl;
  #pragma unroll
  for (int j=0;j<8;j++){ int i = base + j; if (i<n) out[i] = run; run += v[j]; }
}

__global__ void k_scan2(int* __restrict__ partials, int nb, int* __restrict__ out, int n){
  if (threadIdx.x==0 && blockIdx.x==0){
    int run = 0;
    for (int i=0;i<nb;i++){ int x = partials[i]; partials[i] = run; run += x; }
    out[n] = run;
  }
}

__global__ __launch_bounds__(256) void k_scan3(int* __restrict__ out, const int* __restrict__ partials, int n){
  int i = blockIdx.x*256 + threadIdx.x;
  if (i < n) out[i] += partials[i >> 11];
}

// merged XCD-windowed scatter: BOTH CSRs filled in one scan of rec (window = blockIdx&7)
__global__ __launch_bounds__(256) void k_scatter_both(const ull* __restrict__ rec,
    const int* __restrict__ mcountp,
    const int* __restrict__ off_hed, int* __restrict__ cur_hed, unsigned* __restrict__ edge_hed,
    const int* __restrict__ off_slot, int* __restrict__ cur_slot, unsigned* __restrict__ edge_src, int E){
  int w = blockIdx.x & 7;
  int chunk = blockIdx.x >> 3;
  int nchunk = gridDim.x >> 3;
  int per = (E + nchunk - 1) / nchunk;
  int lo_i = chunk * per;
  int hi_i = min(E, lo_i + per);
  int divs = (*mcountp + 7) >> 3;
  for (int i = lo_i + threadIdx.x; i < hi_i; i += 256){
    ull r = rec[i];
    unsigned hed = (unsigned)(r >> 32);
    if (hed == SENT) continue;
    unsigned lo = (unsigned)r;
    int slot = lo & 0xFFFFF;
    if ((int)hed / 2500 == w){
      int p = off_hed[hed] + atomicAdd(&cur_hed[hed], 1);
      edge_hed[p] = lo;
    }
    if (slot / divs == w){
      int p = off_slot[slot] + atomicAdd(&cur_slot[slot], 1);
      edge_src[p] = hed | (lo & 0xFFF00000u);
    }
  }
}

// ================= 4x4 register-blocked GEMM64 =================
#define LOAD_W(Wl, Wsrc) for (int i_=threadIdx.x; i_<1024; i_+=256) ((float4*)Wl)[i_] = ((const float4*)(Wsrc))[i_];

#define STAGE_AT(At, ro, nrows, LOADEXPR)                              \
  {                                                                    \
    int cg_ = threadIdx.x & 15, rl_ = threadIdx.x >> 4;                \
    for (int p_ = 0; p_ < 4; ++p_){                                    \
      int rloc_ = p_*16 + rl_;                                         \
      int r_ = (ro) + rloc_;                                           \
      float4 v_ = make_float4(0.f,0.f,0.f,0.f);                        \
      if (r_ < (nrows)){ v_ = (LOADEXPR); }                            \
      At[cg_*4+0][rloc_] = v_.x;                                       \
      At[cg_*4+1][rloc_] = v_.y;                                       \
      At[cg_*4+2][rloc_] = v_.z;                                       \
      At[cg_*4+3][rloc_] = v_.w;                                       \
    }                                                                  \
  }

__device__ __forceinline__ void gemm44(const float* __restrict__ Wl, const float (*At)[ATP],
                                       int rg4, int cg4, float4 acc[4]){
  #pragma unroll 8
  for (int k = 0; k < 64; ++k){
    const float4 w = *(const float4*)&Wl[k*64 + cg4];
    const float4 a = *(const float4*)&At[k][rg4];
    acc[0].x = fmaf(a.x,w.x,acc[0].x); acc[0].y = fmaf(a.x,w.y,acc[0].y);
    acc[0].z = fmaf(a.x,w.z,acc[0].z); acc[0].w = fmaf(a.x,w.w,acc[0].w);
    acc[1].x = fmaf(a.y,w.x,acc[1].x); acc[1].y = fmaf(a.y,w.y,acc[1].y);
    acc[1].z = fmaf(a.y,w.z,acc[1].z); acc[1].w = fmaf(a.y,w.w,acc[1].w);
    acc[2].x = fmaf(a.z,w.x,acc[2].x); acc[2].y = fmaf(a.z,w.y,acc[2].y);
    acc[2].z = fmaf(a.z,w.z,acc[2].z); acc[2].w = fmaf(a.z,w.w,acc[2].w);
    acc[3].x = fmaf(a.w,w.x,acc[3].x); acc[3].y = fmaf(a.w,w.y,acc[3].y);
    acc[3].z = fmaf(a.w,w.z,acc[3].z); acc[3].w = fmaf(a.w,w.w,acc[3].w);
  }
}

#define ZERO4(a) { a[0]=make_float4(0,0,0,0); a[1]=make_float4(0,0,0,0); a[2]=make_float4(0,0,0,0); a[3]=make_float4(0,0,0,0); }

// rowmatA: nm_bf = bf16(ne[mlist]@Wm) ; inner1 = ne[mlist]@Wi1
__global__ __launch_bounds__(256) void k_rowmatA(const float* __restrict__ ne, const float* __restrict__ Wm,
    const float* __restrict__ Wi1, const int* __restrict__ mlist, const int* __restrict__ mcountp,
    unsigned short* __restrict__ nm_bf, float* __restrict__ inner1){
  __shared__ float W1[4096], W2[4096];
  __shared__ float At[64][ATP];
  int t = threadIdx.x;
  int nrows = *mcountp;
  int ntiles = (nrows + 63) >> 6;
  LOAD_W(W1, Wm)
  LOAD_W(W2, Wi1)
  int cg4 = (t & 15)*4, rg4 = (t >> 4)*4;
  for (int tile = blockIdx.x; tile < ntiles; tile += gridDim.x){
    int ro = tile << 6;
    __syncthreads();
    STAGE_AT(At, ro, nrows, (*(const float4*)&ne[(size_t)mlist[r_]*64 + cg_*4]))
    __syncthreads();
    float4 a1[4]; ZERO4(a1)
    float4 a2[4]; ZERO4(a2)
    #pragma unroll 4
    for (int k = 0; k < 64; ++k){
      const float4 w1 = *(const float4*)&W1[k*64 + cg4];
      const float4 w2 = *(const float4*)&W2[k*64 + cg4];
      const float4 a  = *(const float4*)&At[k][rg4];
      a1[0].x=fmaf(a.x,w1.x,a1[0].x); a1[0].y=fmaf(a.x,w1.y,a1[0].y); a1[0].z=fmaf(a.x,w1.z,a1[0].z); a1[0].w=fmaf(a.x,w1.w,a1[0].w);
      a1[1].x=fmaf(a.y,w1.x,a1[1].x); a1[1].y=fmaf(a.y,w1.y,a1[1].y); a1[1].z=fmaf(a.y,w1.z,a1[1].z); a1[1].w=fmaf(a.y,w1.w,a1[1].w);
      a1[2].x=fmaf(a.z,w1.x,a1[2].x); a1[2].y=fmaf(a.z,w1.y,a1[2].y); a1[2].z=fmaf(a.z,w1.z,a1[2].z); a1[2].w=fmaf(a.z,w1.w,a1[2].w);
      a1[3].x=fmaf(a.w,w1.x,a1[3].x); a1[3].y=fmaf(a.w,w1.y,a1[3].y); a1[3].z=fmaf(a.w,w1.z,a1[3].z); a1[3].w=fmaf(a.w,w1.w,a1[3].w);
      a2[0].x=fmaf(a.x,w2.x,a2[0].x); a2[0].y=fmaf(a.x,w2.y,a2[0].y); a2[0].z=fmaf(a.x,w2.z,a2[0].z); a2[0].w=fmaf(a.x,w2.w,a2[0].w);
      a2[1].x=fmaf(a.y,w2.x,a2[1].x); a2[1].y=fmaf(a.y,w2.y,a2[1].y); a2[1].z=fmaf(a.y,w2.z,a2[1].z); a2[1].w=fmaf(a.y,w2.w,a2[1].w);
      a2[2].x=fmaf(a.z,w2.x,a2[2].x); a2[2].y=fmaf(a.z,w2.y,a2[2].y); a2[2].z=fmaf(a.z,w2.z,a2[2].z); a2[2].w=fmaf(a.z,w2.w,a2[2].w);
      a2[3].x=fmaf(a.w,w2.x,a2[3].x); a2[3].y=fmaf(a.w,w2.y,a2[3].y); a2[3].z=fmaf(a.w,w2.z,a2[3].z); a2[3].w=fmaf(a.w,w2.w,a2[3].w);
    }
    #pragma unroll
    for (int i = 0; i < 4; ++i){
      int r = ro + rg4 + i;
      if (r < nrows){
        ushort4 s;
        s.x = f2bf(a1[i].x); s.y = f2bf(a1[i].y); s.z = f2bf(a1[i].z); s.w = f2bf(a1[i].w);
        *(ushort4*)&nm_bf[(size_t)r*64 + cg4] = s;
        *(float4*)&inner1[(size_t)r*64 + cg4] = a2[i];
      }
    }
  }
}

// rowmatB: hq = he@Wa ; block 0 prologue: smbuf = sema@Wm
__global__ __launch_bounds__(256) void k_rowmatB(const float* __restrict__ he, const float* __restrict__ sema,
    const float* __restrict__ Wa, const float* __restrict__ Wm,
    float* __restrict__ hq, float* __restrict__ smbuf, int H, int NS_){
  __shared__ float W1[4096];
  __shared__ float At[64][ATP];
  int t = threadIdx.x;
  if (blockIdx.x == 0 && t < 160){
    int sr = t >> 4, c4 = (t & 15)*4;
    float4 accs = make_float4(0,0,0,0);
    #pragma unroll 8
    for (int k = 0; k < 64; ++k){
      float a = sema[sr*64 + k];
      float4 w = *(const float4*)&Wm[k*64 + c4];
      accs.x = fmaf(a,w.x,accs.x); accs.y = fmaf(a,w.y,accs.y);
      accs.z = fmaf(a,w.z,accs.z); accs.w = fmaf(a,w.w,accs.w);
    }
    *(float4*)&smbuf[(size_t)sr*64 + c4] = accs;
  }
  LOAD_W(W1, Wa)
  int nrows = H;
  int ntiles = (nrows + 63) >> 6;
  int cg4 = (t & 15)*4, rg4 = (t >> 4)*4;
  for (int tile = blockIdx.x; tile < ntiles; tile += gridDim.x){
    int ro = tile << 6;
    __syncthreads();
    STAGE_AT(At, ro, nrows, (*(const float4*)&he[(size_t)r_*64 + cg_*4]))
    __syncthreads();
    float4 acc[4]; ZERO4(acc)
    gemm44(W1, At, rg4, cg4, acc);
    #pragma unroll
    for (int i = 0; i < 4; ++i){
      int r = ro + rg4 + i;
      if (r < nrows) *(float4*)&hq[(size_t)r*64 + cg4] = acc[i];
    }
  }
}

// matfuse (unchanged from R11)
__global__ __launch_bounds__(256) void k_matfuse(const float* __restrict__ inner1, const float* __restrict__ nagg,
    const float* __restrict__ oagg, const float* __restrict__ Wi2, const float* __restrict__ Wn,
    const float* __restrict__ We, const float* __restrict__ Ws,
    const int* __restrict__ mlist, const int* __restrict__ mcountp, float* __restrict__ ne){
  __shared__ float Wl[4096];
  __shared__ float At[64][ATP];
  int t = threadIdx.x;
  int cnt = *mcountp;
  int ntiles = (cnt + 63) >> 6;
  int cg4 = (t & 15)*4, rg4 = (t >> 4)*4;
  for (int tile = blockIdx.x; tile < ntiles; tile += gridDim.x){
    int ro = tile << 6;
    __syncthreads();
    STAGE_AT(At, ro, cnt, (*(const float4*)&nagg[(size_t)r_*64 + cg_*4]))
    LOAD_W(Wl, Ws)
    __syncthreads();
    float4 acc[4]; ZERO4(acc)
    gemm44(Wl, At, rg4, cg4, acc);   // acc = An@Ws
    __syncthreads();
    LOAD_W(Wl, Wi2)
    __syncthreads();
    float4 p1[4]; ZERO4(p1)
    gemm44(Wl, At, rg4, cg4, p1);    // p1 = An@Wi2
    float x[4][4];
    #pragma unroll
    for (int i = 0; i < 4; ++i){
      int r = ro + rg4 + i;
      float4 v = make_float4(0.f,0.f,0.f,0.f);
      if (r < cnt) v = *(const float4*)&inner1[(size_t)r*64 + cg4];
      float x0 = p1[i].x + v.x, x1 = p1[i].y + v.y, x2 = p1[i].z + v.z, x3 = p1[i].w + v.w;
      x[i][0] = x0 >= 0.f ? x0 : 0.01f*x0;
      x[i][1] = x1 >= 0.f ? x1 : 0.01f*x1;
      x[i][2] = x2 >= 0.f ? x2 : 0.01f*x2;
      x[i][3] = x3 >= 0.f ? x3 : 0.01f*x3;
    }
    __syncthreads();
    #pragma unroll
    for (int i = 0; i < 4; ++i)
      #pragma unroll
      for (int j = 0; j < 4; ++j)
        At[cg4+j][rg4+i] = x[i][j];
    LOAD_W(Wl, Wn)
    __syncthreads();
    gemm44(Wl, At, rg4, cg4, acc);   // acc += Ai@Wn
    __syncthreads();
    STAGE_AT(At, ro, cnt, (*(const float4*)&oagg[(size_t)r_*64 + cg_*4]))
    LOAD_W(Wl, We)
    __syncthreads();
    gemm44(Wl, At, rg4, cg4, acc);   // acc += Ao@We
    #pragma unroll
    for (int i = 0; i < 4; ++i){
      int r = ro + rg4 + i;
      if (r < cnt){
        float4 o = make_float4(tanhf(acc[i].x), tanhf(acc[i].y), tanhf(acc[i].z), tanhf(acc[i].w));
        *(float4*)&ne[(size_t)mlist[r]*64 + cg4] = o;
      }
    }
  }
}

// ---------------- attention + W_upd matvec fused; bf16 nm gathers ----------------
__global__ __launch_bounds__(256) void k_attn_upd(const int* __restrict__ off_hed, const unsigned* __restrict__ edge_hed,
    const unsigned short* __restrict__ nm_bf, const float* __restrict__ smb, const float* __restrict__ hq,
    const float* __restrict__ W, const float* __restrict__ he_cur, float* __restrict__ he_next,
    unsigned short* __restrict__ he_bf, int H){
  __shared__ float Wl[4096];
  __shared__ float sm_lds[640];
  __shared__ float aggl[256];
  int t = threadIdx.x;
  for (int i=t;i<1024;i+=256) ((float4*)Wl)[i] = ((const float4*)W)[i];
  for (int i=t;i<640;i+=256) sm_lds[i] = smb[i];
  __syncthreads();
  int w = t >> 6, lane = t & 63;
  int nhb = (H + 3) >> 2;
  for (int hb = blockIdx.x; hb < nhb; hb += gridDim.x){
    int h = hb*4 + w;
    if (h >= H) continue;
    int start = off_hed[h], end = off_hed[h+1];
    if (start == end){
      float v = he_cur[(size_t)h*64 + lane];
      he_next[(size_t)h*64 + lane] = v;
      he_bf[(size_t)h*64 + lane] = f2bf(v);
      continue;
    }
    int g = lane >> 4, dl = (lane & 15)*4;
    float4 q4 = *(const float4*)&hq[(size_t)h*64 + dl];
    float ax=0.f, ay=0.f, az=0.f, aw=0.f, dsum=0.f, m=-3.4e38f;
    for (int idx0 = start; idx0 < end; idx0 += 4){
      int idx = idx0 + g;
      bool valid = idx < end;
      unsigned u = valid ? edge_hed[idx] : 0u;
      int slot = u & 0xFFFFF, sem = u >> 20;
      float4 nm4 = make_float4(0.f,0.f,0.f,0.f);
      if (valid){
        ushort4 nu = *(const ushort4*)&nm_bf[(size_t)slot*64 + dl];
        nm4 = make_float4(bf2f(nu.x), bf2f(nu.y), bf2f(nu.z), bf2f(nu.w));
      }
      float4 sm4 = *(const float4*)&sm_lds[sem*64 + dl];
      float mkx = nm4.x+sm4.x, mky = nm4.y+sm4.y, mkz = nm4.z+sm4.z, mkw = nm4.w+sm4.w;
      float part = mkx*q4.x + mky*q4.y + mkz*q4.z + mkw*q4.w;
      part = group16_sum(part);
      float l = valid ? part : -3.4e38f;
      float mn = fmaxf(m, l);
      float scale = __expf(m - mn);
      float wgt = valid ? __expf(l - mn) : 0.f;
      ax = ax*scale + wgt*mkx; ay = ay*scale + wgt*mky;
      az = az*scale + wgt*mkz; aw = aw*scale + wgt*mkw;
      dsum = dsum*scale + wgt;
      m = mn;
    }
    float mg = fmaxf(m, __shfl_xor(m, 16, 64));
    mg = fmaxf(mg, __shfl_xor(mg, 32, 64));
    float cs = __expf(m - mg);
    ax*=cs; ay*=cs; az*=cs; aw*=cs; dsum*=cs;
    ax = xgroup_sum(ax); ay = xgroup_sum(ay); az = xgroup_sum(az); aw = xgroup_sum(aw);
    dsum = xgroup_sum(dsum);
    if (lane < 16){
      float inv = 1.f/(dsum + EPSF);
      aggl[w*64 + dl+0] = ax*inv;
      aggl[w*64 + dl+1] = ay*inv;
      aggl[w*64 + dl+2] = az*inv;
      aggl[w*64 + dl+3] = aw*inv;
    }
    float o = 0.f;
    #pragma unroll 8
    for (int j=0;j<64;j++) o = fmaf(aggl[w*64 + j], Wl[j*64 + lane], o);
    float ov = tanhf(o);
    he_next[(size_t)h*64 + lane] = ov;
    he_bf[(size_t)h*64 + lane] = f2bf(ov);
  }
}

// ---------------- per-member-slot aggregation; bf16 he gathers ----------------
__global__ __launch_bounds__(256) void k_nodeagg2(const int* __restrict__ mcountp,
    const int* __restrict__ off_slot, const unsigned* __restrict__ edge_src,
    const unsigned short* __restrict__ he_bf, const float* __restrict__ sema,
    float* __restrict__ nagg, float* __restrict__ oagg){
  __shared__ float sm_lds[640];
  int t = threadIdx.x;
  for (int i=t;i<640;i+=256) sm_lds[i] = sema[i];
  __syncthreads();
  int w = t >> 6, lane = t & 63;
  int mc = *mcountp;
  int npb = (mc + 3) >> 2;
  int g = lane >> 4, dl = (lane & 15)*4;
  for (int pb = blockIdx.x; pb < npb; pb += gridDim.x){
    int p = pb*4 + w;
    if (p >= mc) continue;
    int start = off_slot[p], end = off_slot[p+1];
    float anx=0.f, any_=0.f, anz=0.f, anw=0.f;
    float aox=0.f, aoy=0.f, aoz=0.f, aow=0.f;
    for (int idx0 = start; idx0 < end; idx0 += 4){
      int idx = idx0 + g;
      if (idx < end){
        unsigned u = edge_src[idx];
        int hd = u & 0xFFFFF, sem = u >> 20;
        ushort4 hu = *(const ushort4*)&he_bf[(size_t)hd*64 + dl];
        float4 hv = make_float4(bf2f(hu.x), bf2f(hu.y), bf2f(hu.z), bf2f(hu.w));
        float4 sv = *(const float4*)&sm_lds[sem*64 + dl];
        anx += hv.x; any_ += hv.y; anz += hv.z; anw += hv.w;
        aox = fmaf(hv.x, sv.x, aox); aoy = fmaf(hv.y, sv.y, aoy);
        aoz = fmaf(hv.z, sv.z, aoz); aow = fmaf(hv.w, sv.w, aow);
      }
    }
    anx = xgroup_sum(anx); any_ = xgroup_sum(any_); anz = xgroup_sum(anz); anw = xgroup_sum(anw);
    aox = xgroup_sum(aox); aoy = xgroup_sum(aoy); aoz = xgroup_sum(aoz); aow = xgroup_sum(aow);
    if (lane < 16){
      float inv = 1.f/((float)(end - start) + EPSF);
      *(float4*)&nagg[(size_t)p*64 + dl] = make_float4(anx*inv, any_*inv, anz*inv, anw*inv);
      *(float4*)&oagg[(size_t)p*64 + dl] = make_float4(aox*inv, aoy*inv, aoz*inv, aow*inv);
    }
  }
}

extern "C" void kernel_launch(void* const* d_in, const int* in_sizes, int n_in,
                              void* d_out, int out_size, void* d_ws, size_t ws_size,
                              hipStream_t stream)
{
  (void)in_sizes; (void)n_in; (void)out_size; (void)ws_size;
  const float* node_emb  = (const float*)d_in[0];
  const float* hyper_emb = (const float*)d_in[1];
  const float* sema_emb  = (const float*)d_in[2];
  const float* W_msg = (const float*)d_in[3];
  const float* W_att = (const float*)d_in[4];
  const float* W_upd = (const float*)d_in[5];
  const float* Wi1   = (const float*)d_in[6];
  const float* Wi2   = (const float*)d_in[7];
  const float* Wo_n  = (const float*)d_in[8];
  const float* Wo_e  = (const float*)d_in[9];
  const float* Wo_s  = (const float*)d_in[10];
  const int* node_indices = (const int*)d_in[11];
  const int* semalinks    = (const int*)d_in[14];

  constexpr int N = 100000, H = 20000, NS = 10, L = 2, E = 1000000, NB = 50000;

  float* out_ne = (float*)d_out;                    // N*64
  float* out_he = (float*)d_out + (size_t)N*64;     // H*64

  char* wsp = (char*)d_ws;
  auto alloc = [&](size_t bytes)->char*{ char* p = wsp; wsp += (bytes + 255) & ~(size_t)255; return p; };
  char* zstart = wsp;
  int* member   = (int*)alloc((size_t)N*4);
  int* cnt_hed  = (int*)alloc((size_t)H*4);
  int* cnt_slot = (int*)alloc((size_t)NSLOT*4);
  int* cur_hed  = (int*)alloc((size_t)H*4);
  int* cur_slot = (int*)alloc((size_t)NSLOT*4);
  int* mcount   = (int*)alloc(256);
  size_t zbytes = (size_t)(wsp - zstart);
  int* off_hed   = (int*)alloc((size_t)(H+1)*4);
  int* off_slot  = (int*)alloc((size_t)(NSLOT+1)*4);
  int* mlist     = (int*)alloc((size_t)NB*4);
  int* partials  = (int*)alloc(256);
  ull* rec       = (ull*)alloc((size_t)E*8);
  unsigned* edge_hed = (unsigned*)alloc((size_t)E*4);
  unsigned* edge_src = (unsigned*)alloc((size_t)E*4);
  float* smbuf  = (float*)alloc((size_t)NS*64*4);
  float* hq     = (float*)alloc((size_t)H*64*4);
  unsigned short* nm_bf = (unsigned short*)alloc((size_t)NB*64*2);
  unsigned short* he_bf = (unsigned short*)alloc((size_t)H*64*2);
  float* he1    = (float*)alloc((size_t)H*64*4);
  float* naggb  = (float*)alloc((size_t)NB*64*4);
  float* oaggb  = (float*)alloc((size_t)NB*64*4);
  float* inner1 = (float*)alloc((size_t)NB*64*4);

  hipMemsetAsync(zstart, 0, zbytes, stream);

  k_copy4<<<(N*64/4 + 255)/256, 256, 0, stream>>>((const float4*)node_emb, (float4*)out_ne, N*64/4);
  k_set_member<<<(NB+255)/256, 256, 0, stream>>>(node_indices, member, NB);
  k_build_list<<<(N+255)/256, 256, 0, stream>>>(member, mlist, mcount, N);
  k_count_rec<<<(E+255)/256, 256, 0, stream>>>(semalinks, member, rec, cnt_hed, cnt_slot, E);

  int nb_h = (H + 2047)/2048, nb_s = (NSLOT + 2047)/2048;
  k_scan1<<<nb_h, 256, 0, stream>>>(cnt_hed, off_hed, H, partials);
  k_scan2<<<1, 64, 0, stream>>>(partials, nb_h, off_hed, H);
  k_scan3<<<(H+255)/256, 256, 0, stream>>>(off_hed, partials, H);
  k_scan1<<<nb_s, 256, 0, stream>>>(cnt_slot, off_slot, NSLOT, partials);
  k_scan2<<<1, 64, 0, stream>>>(partials, nb_s, off_slot, NSLOT);
  k_scan3<<<(NSLOT+255)/256, 256, 0, stream>>>(off_slot, partials, NSLOT);

  k_scatter_both<<<1024, 256, 0, stream>>>(rec, mcount, off_hed, cur_hed, edge_hed,
                                           off_slot, cur_slot, edge_src, E);

  for (int i = 0; i < L; ++i){
    const float* Wm = W_msg + (size_t)i*4096;
    const float* Wa = W_att + (size_t)i*4096;
    const float* Wu = W_upd + (size_t)i*4096;
    const float* wi1 = Wi1 + (size_t)i*4096;
    const float* wi2 = Wi2 + (size_t)i*4096;
    const float* won = Wo_n + (size_t)i*4096;
    const float* woe = Wo_e + (size_t)i*4096;
    const float* wos = Wo_s + (size_t)i*4096;
    const float* he_cur = (i == 0) ? hyper_emb : he1;
    float* he_next = (i == 0) ? he1 : out_he;

    k_rowmatA<<<800, 256, 0, stream>>>(out_ne, Wm, wi1, mlist, mcount, nm_bf, inner1);
    k_rowmatB<<<320, 256, 0, stream>>>(he_cur, sema_emb, Wa, Wm, hq, smbuf, H, NS);
    k_attn_upd<<<1280, 256, 0, stream>>>(off_hed, edge_hed, nm_bf, smbuf, hq, Wu, he_cur, he_next, he_bf, H);
    k_nodeagg2<<<1280, 256, 0, stream>>>(mcount, off_slot, edge_src, he_bf, sema_emb, naggb, oaggb);
    k_matfuse<<<800, 256, 0, stream>>>(inner1, naggb, oaggb, wi2, won, woe, wos, mlist, mcount, out_ne);
  }
}